// Round 4
// baseline (1094.060 us; speedup 1.0000x reference)
//
#include <hip/hip_runtime.h>

#define NTOK 16384
#define DIN  512
#define DOUT 512
#define HDIM 256
#define NEXP 10
#define ARENA_BYTES ((size_t)2 * NTOK * DOUT * 4)   // d_out bytes (f32)

typedef unsigned short u16;
typedef unsigned int   u32;
typedef short s16x8 __attribute__((ext_vector_type(8)));
typedef float f32x4 __attribute__((ext_vector_type(4)));

__device__ __forceinline__ u16 f2b(float f){
  union { float f; u32 u; } c; c.f = f;
  u32 r = c.u + 0x7FFFu + ((c.u >> 16) & 1u);
  return (u16)(r >> 16);
}
// 8 consecutive f32 -> bf16x8 fragment (round-to-nearest-even)
__device__ __forceinline__ s16x8 cvt8(const float* p){
  f32x4 a = *(const f32x4*)p;
  f32x4 b = *(const f32x4*)(p + 4);
  s16x8 r;
  r[0]=(short)f2b(a[0]); r[1]=(short)f2b(a[1]); r[2]=(short)f2b(a[2]); r[3]=(short)f2b(a[3]);
  r[4]=(short)f2b(b[0]); r[5]=(short)f2b(b[1]); r[6]=(short)f2b(b[2]); r[7]=(short)f2b(b[3]);
  return r;
}

// ---------------- gating: one wave per token, all f32 ----------------
__global__ __launch_bounds__(256) void k_gate(
    const float* __restrict__ x, const float* __restrict__ gw, const float* __restrict__ gb,
    int* __restrict__ topk_e, float* __restrict__ topk_w)
{
  const int wave = threadIdx.x >> 6, lane = threadIdx.x & 63;
  const int token = blockIdx.x * 4 + wave;
  float acc[NEXP];
  #pragma unroll
  for (int e = 0; e < NEXP; ++e) acc[e] = 0.f;
  const float* xr = x + (size_t)token * DIN;
  #pragma unroll
  for (int i = 0; i < DIN/64; ++i){
    int d = lane + 64*i;
    float xv = xr[d];
    const float* g = gw + (size_t)d * NEXP;
    #pragma unroll
    for (int e = 0; e < NEXP; ++e) acc[e] += xv * g[e];
  }
  #pragma unroll
  for (int e = 0; e < NEXP; ++e){
    #pragma unroll
    for (int off = 32; off > 0; off >>= 1) acc[e] += __shfl_xor(acc[e], off, 64);
  }
  if (lane == 0){
    float l[NEXP];
    #pragma unroll
    for (int e = 0; e < NEXP; ++e) l[e] = acc[e] + gb[e];
    int bi = 0; float bv = l[0];
    #pragma unroll
    for (int e = 1; e < NEXP; ++e) if (l[e] > bv){ bv = l[e]; bi = e; }
    int si = -1; float sv = -1e30f;
    #pragma unroll
    for (int e = 0; e < NEXP; ++e) if (e != bi && l[e] > sv){ sv = l[e]; si = e; }
    float w0 = 1.f / (1.f + expf(sv - bv));   // renormalized softmax pair (exact)
    topk_e[2*token]   = bi;  topk_e[2*token+1] = si;
    topk_w[2*token]   = w0;  topk_w[2*token+1] = 1.f - w0;
  }
}

// ---------------- fused dense MoE: 64 tokens/block, all 10 experts ----------------
// combined[t] = sum_e wexp[t][e] * ( relu(x_t W1e + b1e) W2e + b2e )   (f32 out)
__global__ __launch_bounds__(512) void k_moe(
    const float* __restrict__ x,
    const float* __restrict__ w1, const float* __restrict__ b1,
    const float* __restrict__ w2, const float* __restrict__ b2,
    const int* __restrict__ topk_e, const float* __restrict__ topk_w,
    float* __restrict__ combined)
{
  __shared__ u32   WTu[512][20];           // bf16-pair-packed transposed weight k-tile
  __shared__ u16   hbuf[64][HDIM + 8];     // h tile, bf16, padded
  __shared__ float wexp[64][NEXP];

  const int tid  = threadIdx.x;
  const int tile = blockIdx.x;

  if (tid < 64){
    int tok = tile*64 + tid;
    int e0 = topk_e[2*tok], e1 = topk_e[2*tok+1];
    float v0 = topk_w[2*tok], v1 = topk_w[2*tok+1];
    #pragma unroll
    for (int e = 0; e < NEXP; ++e)
      wexp[tid][e] = (e == e0) ? v0 : ((e == e1) ? v1 : 0.f);
  }

  const int wave = tid >> 6, lane = tid & 63;
  const int lr = lane & 15, lk = lane >> 4;
  const int rowg = wave >> 2;              // 0..1
  const int colg = wave & 3;               // 0..3
  const int kr2 = (tid >> 5) * 2;          // staging k-row pair 0..30
  const int c8  = tid & 31;                // staging col group (8 cols)

  f32x4 comb[2][8];
  #pragma unroll
  for (int i = 0; i < 2; ++i)
    #pragma unroll
    for (int j = 0; j < 8; ++j) comb[i][j] = (f32x4){0.f,0.f,0.f,0.f};

  __syncthreads();   // wexp ready

  f32x4 s0a, s0b, s1a, s1b;
  for (int e = 0; e < NEXP; ++e){
    const float* w1e = w1 + (size_t)e * DIN * HDIM;
    // -------- phase 1: h = relu(X W1e + b1e) --------
    f32x4 acc1[2][4];
    #pragma unroll
    for (int i = 0; i < 2; ++i)
      #pragma unroll
      for (int j = 0; j < 4; ++j) acc1[i][j] = (f32x4){0.f,0.f,0.f,0.f};

    { const float* src = w1e + (size_t)kr2 * HDIM + c8*8;
      s0a = *(const f32x4*)src;          s0b = *(const f32x4*)(src + 4);
      s1a = *(const f32x4*)(src + HDIM); s1b = *(const f32x4*)(src + HDIM + 4); }

    for (int ks = 0; ks < DIN/32; ++ks){
      __syncthreads();                     // prior WTu readers done
      #pragma unroll
      for (int m = 0; m < 4; ++m){
        WTu[c8*8+m  ][kr2>>1] = (u32)f2b(s0a[m]) | ((u32)f2b(s1a[m]) << 16);
        WTu[c8*8+4+m][kr2>>1] = (u32)f2b(s0b[m]) | ((u32)f2b(s1b[m]) << 16);
      }
      __syncthreads();                     // WTu ready
      if (ks + 1 < DIN/32){
        const float* src = w1e + (size_t)((ks+1)*32 + kr2) * HDIM + c8*8;
        s0a = *(const f32x4*)src;          s0b = *(const f32x4*)(src + 4);
        s1a = *(const f32x4*)(src + HDIM); s1b = *(const f32x4*)(src + HDIM + 4);
      }
      s16x8 a[2];
      #pragma unroll
      for (int i = 0; i < 2; ++i){
        int row = tile*64 + rowg*32 + i*16 + lr;
        a[i] = cvt8(x + (size_t)row * DIN + ks*32 + lk*8);
      }
      #pragma unroll
      for (int j = 0; j < 4; ++j){
        int col = colg*64 + j*16 + lr;
        s16x8 bfrag = *(const s16x8*)((const u16*)(&WTu[col][0]) + lk*8);
        #pragma unroll
        for (int i = 0; i < 2; ++i)
          acc1[i][j] = __builtin_amdgcn_mfma_f32_16x16x32_bf16(a[i], bfrag, acc1[i][j], 0, 0, 0);
      }
    }
    #pragma unroll
    for (int j = 0; j < 4; ++j){
      int col = colg*64 + j*16 + lr;
      float bias = b1[e*HDIM + col];
      #pragma unroll
      for (int i = 0; i < 2; ++i)
        #pragma unroll
        for (int r = 0; r < 4; ++r){
          int row = rowg*32 + i*16 + lk*4 + r;
          float v = acc1[i][j][r] + bias;
          hbuf[row][col] = f2b(v > 0.f ? v : 0.f);
        }
    }
    __syncthreads();                       // hbuf ready; phase-1 WTu reads drained

    // -------- phase 2: y = h W2e + b2e, combine --------
    const float* w2e = w2 + (size_t)e * HDIM * DOUT;
    #pragma unroll
    for (int hf = 0; hf < 2; ++hf){
      f32x4 acc2[2][4];
      #pragma unroll
      for (int i = 0; i < 2; ++i)
        #pragma unroll
        for (int j = 0; j < 4; ++j) acc2[i][j] = (f32x4){0.f,0.f,0.f,0.f};

      { const float* src = w2e + (size_t)kr2 * DOUT + hf*256 + c8*8;
        s0a = *(const f32x4*)src;          s0b = *(const f32x4*)(src + 4);
        s1a = *(const f32x4*)(src + DOUT); s1b = *(const f32x4*)(src + DOUT + 4); }

      for (int ks = 0; ks < HDIM/32; ++ks){
        __syncthreads();
        #pragma unroll
        for (int m = 0; m < 4; ++m){
          WTu[c8*8+m  ][kr2>>1] = (u32)f2b(s0a[m]) | ((u32)f2b(s1a[m]) << 16);
          WTu[c8*8+4+m][kr2>>1] = (u32)f2b(s0b[m]) | ((u32)f2b(s1b[m]) << 16);
        }
        __syncthreads();
        if (ks + 1 < HDIM/32){
          const float* src = w2e + (size_t)((ks+1)*32 + kr2) * DOUT + hf*256 + c8*8;
          s0a = *(const f32x4*)src;          s0b = *(const f32x4*)(src + 4);
          s1a = *(const f32x4*)(src + DOUT); s1b = *(const f32x4*)(src + DOUT + 4);
        }
        s16x8 a[2];
        #pragma unroll
        for (int i = 0; i < 2; ++i)
          a[i] = *(const s16x8*)(&hbuf[rowg*32 + i*16 + lr][ks*32 + lk*8]);
        #pragma unroll
        for (int j = 0; j < 4; ++j){
          int col = colg*64 + j*16 + lr;
          s16x8 bfrag = *(const s16x8*)((const u16*)(&WTu[col][0]) + lk*8);
          #pragma unroll
          for (int i = 0; i < 2; ++i)
            acc2[i][j] = __builtin_amdgcn_mfma_f32_16x16x32_bf16(a[i], bfrag, acc2[i][j], 0, 0, 0);
        }
      }
      #pragma unroll
      for (int j = 0; j < 4; ++j){
        int col = hf*256 + colg*64 + j*16 + lr;
        float bias = b2[e*DOUT + col];
        #pragma unroll
        for (int i = 0; i < 2; ++i)
          #pragma unroll
          for (int r = 0; r < 4; ++r){
            int row = rowg*32 + i*16 + lk*4 + r;
            comb[i][hf*4+j][r] += wexp[row][e] * (acc2[i][j][r] + bias);
          }
      }
      __syncthreads();   // drain this hf's WTu/hbuf reads before next staging
    }
  }

  // epilogue: combined tile write (f32)
  #pragma unroll
  for (int hf = 0; hf < 2; ++hf)
    #pragma unroll
    for (int j = 0; j < 4; ++j)
      #pragma unroll
      for (int i = 0; i < 2; ++i)
        #pragma unroll
        for (int r = 0; r < 4; ++r){
          int row = tile*64 + rowg*32 + i*16 + lk*4 + r;
          int col = hf*256 + colg*64 + j*16 + lr;
          combined[(size_t)row * DOUT + col] = comb[i][hf*4+j][r];
        }
}

// ---------------- final GEMM: out(f32) = A(f32, 64-row tile) @ W(f32) + bias ----------------
// bf16 MFMA internally. Safe in place (out == A): block reads only its own
// 64-row stripe; barrier after the k-loop drains reads before epilogue writes.
__global__ __launch_bounds__(256) void k_final(
    const float* __restrict__ A, const float* __restrict__ W,
    const float* __restrict__ bias, float* __restrict__ out)
{
  __shared__ u32 WTu[512][20];
  const int tid  = threadIdx.x;
  const int wave = tid >> 6, lane = tid & 63;
  const int lr = lane & 15, lk = lane >> 4;
  const int rowg = wave >> 1;              // rows rowg*32
  const int colg = wave & 1;               // cols colg*256
  const int kr2 = (tid >> 4) * 2;          // 0..30
  const int c32 = tid & 15;                // col group of 32

  f32x4 acc[2][16];
  #pragma unroll
  for (int i = 0; i < 2; ++i)
    #pragma unroll
    for (int j = 0; j < 16; ++j) acc[i][j] = (f32x4){0.f,0.f,0.f,0.f};

  f32x4 r0[8], r1[8];
  { const float* src = W + (size_t)kr2 * DOUT + c32*32;
    #pragma unroll
    for (int q = 0; q < 8; ++q){
      r0[q] = *(const f32x4*)(src + q*4);
      r1[q] = *(const f32x4*)(src + DOUT + q*4);
    } }

  for (int ks = 0; ks < DOUT/32; ++ks){
    __syncthreads();
    #pragma unroll
    for (int q = 0; q < 8; ++q)
      #pragma unroll
      for (int m = 0; m < 4; ++m)
        WTu[c32*32 + q*4 + m][kr2>>1] = (u32)f2b(r0[q][m]) | ((u32)f2b(r1[q][m]) << 16);
    __syncthreads();
    if (ks + 1 < DOUT/32){
      const float* src = W + (size_t)((ks+1)*32 + kr2) * DOUT + c32*32;
      #pragma unroll
      for (int q = 0; q < 8; ++q){
        r0[q] = *(const f32x4*)(src + q*4);
        r1[q] = *(const f32x4*)(src + DOUT + q*4);
      }
    }
    s16x8 a[2];
    #pragma unroll
    for (int i = 0; i < 2; ++i){
      int row = blockIdx.x*64 + rowg*32 + i*16 + lr;
      a[i] = cvt8(A + (size_t)row * DOUT + ks*32 + lk*8);
    }
    #pragma unroll
    for (int j = 0; j < 16; ++j){
      int col = colg*256 + j*16 + lr;
      s16x8 bfrag = *(const s16x8*)((const u16*)(&WTu[col][0]) + lk*8);
      #pragma unroll
      for (int i = 0; i < 2; ++i)
        acc[i][j] = __builtin_amdgcn_mfma_f32_16x16x32_bf16(a[i], bfrag, acc[i][j], 0, 0, 0);
    }
  }
  __syncthreads();   // drain ALL A-reads in the block before in-place overwrite

  #pragma unroll
  for (int j = 0; j < 16; ++j){
    int col = colg*256 + j*16 + lr;
    float bv = bias[col];
    #pragma unroll
    for (int i = 0; i < 2; ++i)
      #pragma unroll
      for (int r = 0; r < 4; ++r){
        int row = blockIdx.x*64 + rowg*32 + i*16 + lk*4 + r;
        out[(size_t)row * DOUT + col] = acc[i][j][r] + bv;
      }
  }
}

extern "C" void kernel_launch(void* const* d_in, const int* in_sizes, int n_in,
                              void* d_out, int out_size, void* d_ws, size_t ws_size,
                              hipStream_t stream)
{
  const float* x    = (const float*)d_in[0];
  const float* gw   = (const float*)d_in[1];
  const float* gb   = (const float*)d_in[2];
  const float* w1   = (const float*)d_in[3];
  const float* b1   = (const float*)d_in[4];
  const float* w2   = (const float*)d_in[5];
  const float* b2   = (const float*)d_in[6];
  const float* clsw = (const float*)d_in[7];
  const float* clsb = (const float*)d_in[8];
  const float* vecw = (const float*)d_in[9];
  const float* vecb = (const float*)d_in[10];

  float* out = (float*)d_out;
  // Routing metadata carved from the TAIL of d_out (vec region; consumed by
  // k_moe, then legitimately overwritten by the vec GEMM). Zero d_ws usage.
  int*   tke = (int*)  ((char*)d_out + ARENA_BYTES - 262144);
  float* tkw = (float*)((char*)d_out + ARENA_BYTES - 131072);
  float* combined = out;                           // d_out[0 : N*DOUT) f32
  float* vec_out  = out + (size_t)NTOK * DOUT;     // second half

  k_gate<<<dim3(NTOK/4), dim3(256), 0, stream>>>(x, gw, gb, tke, tkw);
  k_moe<<<dim3(NTOK/64), dim3(512), 0, stream>>>(x, w1, b1, w2, b2, tke, tkw, combined);
  k_final<<<dim3(NTOK/64), dim3(256), 0, stream>>>(combined, vecw, vecb, vec_out);  // clobbers tke/tkw (consumed)
  k_final<<<dim3(NTOK/64), dim3(256), 0, stream>>>(combined, clsw, clsb, combined); // in place
}

// Round 6
// 641.126 us; speedup vs baseline: 1.7065x; 1.7065x over previous
//
#include <hip/hip_runtime.h>

#define NTOK 16384
#define DIN  512
#define DOUT 512
#define HDIM 256
#define NEXP 10
#define NSEG  (2*NEXP)        // (expert, slot-rank) segments

typedef unsigned short u16;
typedef unsigned int   u32;
typedef short s16x8 __attribute__((ext_vector_type(8)));
typedef float f32x4 __attribute__((ext_vector_type(4)));

__device__ __forceinline__ u16 f2b(float f){
  union { float f; u32 u; } c; c.f = f;
  u32 r = c.u + 0x7FFFu + ((c.u >> 16) & 1u);
  return (u16)(r >> 16);
}
__device__ __forceinline__ s16x8 cvt8(const float* p){
  f32x4 a = *(const f32x4*)p;
  f32x4 b = *(const f32x4*)(p + 4);
  s16x8 r;
  r[0]=(short)f2b(a[0]); r[1]=(short)f2b(a[1]); r[2]=(short)f2b(a[2]); r[3]=(short)f2b(a[3]);
  r[4]=(short)f2b(b[0]); r[5]=(short)f2b(b[1]); r[6]=(short)f2b(b[2]); r[7]=(short)f2b(b[3]);
  return r;
}

__global__ __launch_bounds__(64) void k_zero(int* counts){
  if (threadIdx.x < NSEG) counts[threadIdx.x] = 0;
}

// ---------------- gating: one wave per token ----------------
__global__ __launch_bounds__(256) void k_gate(
    const float* __restrict__ x, const float* __restrict__ gw, const float* __restrict__ gb,
    int* __restrict__ tke, float* __restrict__ tkw, int* __restrict__ counts)
{
  __shared__ int cnt[NSEG];
  if (threadIdx.x < NSEG) cnt[threadIdx.x] = 0;
  __syncthreads();
  const int wave = threadIdx.x >> 6, lane = threadIdx.x & 63;
  const int token = blockIdx.x * 4 + wave;
  float acc[NEXP];
  #pragma unroll
  for (int e = 0; e < NEXP; ++e) acc[e] = 0.f;
  const float* xr = x + (size_t)token * DIN;
  #pragma unroll
  for (int i = 0; i < DIN/64; ++i){
    int d = lane + 64*i;
    float xv = xr[d];
    const float* g = gw + (size_t)d * NEXP;
    #pragma unroll
    for (int e = 0; e < NEXP; ++e) acc[e] += xv * g[e];
  }
  #pragma unroll
  for (int e = 0; e < NEXP; ++e){
    #pragma unroll
    for (int off = 32; off > 0; off >>= 1) acc[e] += __shfl_xor(acc[e], off, 64);
  }
  if (lane == 0){
    float l[NEXP];
    #pragma unroll
    for (int e = 0; e < NEXP; ++e) l[e] = acc[e] + gb[e];
    int bi = 0; float bv = l[0];
    #pragma unroll
    for (int e = 1; e < NEXP; ++e) if (l[e] > bv){ bv = l[e]; bi = e; }
    int si = -1; float sv = -1e30f;
    #pragma unroll
    for (int e = 0; e < NEXP; ++e) if (e != bi && l[e] > sv){ sv = l[e]; si = e; }
    float w0 = 1.f / (1.f + expf(sv - bv));   // renormalized softmax pair
    tke[2*token]   = bi;  tke[2*token+1] = si;
    tkw[2*token]   = w0;  tkw[2*token+1] = 1.f - w0;
    atomicAdd(&cnt[2*bi], 1);  atomicAdd(&cnt[2*si+1], 1);
  }
  __syncthreads();
  if (threadIdx.x < NSEG && cnt[threadIdx.x] > 0)
    atomicAdd(&counts[threadIdx.x], cnt[threadIdx.x]);
}

__global__ __launch_bounds__(64) void k_scan(
    const int* __restrict__ counts, int* __restrict__ offsets, int* __restrict__ cursors)
{
  if (threadIdx.x == 0){
    int s = 0;
    for (int i = 0; i < NSEG; ++i){ offsets[i] = s; s += counts[i]; }
    offsets[NSEG] = s;
  }
  if (threadIdx.x < NSEG) cursors[threadIdx.x] = 0;
}

__global__ __launch_bounds__(256) void k_scatter(
    const int* __restrict__ tke, const float* __restrict__ tkw,
    const int* __restrict__ offsets, int* __restrict__ cursors,
    int* __restrict__ tok_slot, float* __restrict__ w_slot)
{
  __shared__ int lcnt[NSEG], lbase[NSEG];
  if (threadIdx.x < NSEG) lcnt[threadIdx.x] = 0;
  __syncthreads();
  int n = blockIdx.x * 256 + threadIdx.x;
  int g0 = 2*tke[2*n], g1 = 2*tke[2*n+1] + 1;
  int p0 = atomicAdd(&lcnt[g0], 1);
  int p1 = atomicAdd(&lcnt[g1], 1);
  __syncthreads();
  if (threadIdx.x < NSEG) lbase[threadIdx.x] = atomicAdd(&cursors[threadIdx.x], lcnt[threadIdx.x]);
  __syncthreads();
  int s0 = offsets[g0] + lbase[g0] + p0;
  int s1 = offsets[g1] + lbase[g1] + p1;
  tok_slot[s0] = n; w_slot[s0] = tkw[2*n];
  tok_slot[s1] = n; w_slot[s1] = tkw[2*n+1];
}

// ---------------- k_h: h = relu(X W1e + b1e), weight-stationary ----------------
// block: (chunk of 256 slots) x (64 h-cols, quarter hq) of expert e. 64KB LDS.
__global__ __launch_bounds__(512) void k_h(
    const float* __restrict__ x, const float* __restrict__ w1, const float* __restrict__ b1,
    const int* __restrict__ offsets, const int* __restrict__ tok_slot,
    u16* __restrict__ h)
{
  __shared__ u16 lw[64*512];        // W1e^T quarter [64 cols][512 k], swizzled
  __shared__ int toks[256];
  const int e  = blockIdx.z;
  const int hq = blockIdx.y;
  const int off = offsets[2*e];
  const int cnt = offsets[2*e+2] - off;
  const int c0  = blockIdx.x * 256;
  if (c0 >= cnt) return;
  const int tid = threadIdx.x;
  {
    const float* wsrc = w1 + (size_t)e * DIN * HDIM + hq*64;
    int n4 = (tid & 15) * 4;                 // col 0..60
    int k0 = tid >> 4;                       // 0..31
    for (int it = 0; it < 16; ++it){
      int k = k0 + it*32;
      f32x4 v = *(const f32x4*)(wsrc + (size_t)k * HDIM + n4);
      #pragma unroll
      for (int i = 0; i < 4; ++i){
        int row = n4 + i;
        u32 byt = (u32)(row*1024 + k*2) ^ (u32)((row & 7) << 4);
        *(u16*)((char*)lw + byt) = f2b(v[i]);
      }
    }
  }
  if (tid < 256){
    int r = c0 + tid;
    toks[tid] = tok_slot[off + (r < cnt ? r : cnt - 1)];
  }
  __syncthreads();

  const int wv = tid >> 6, lane = tid & 63;
  const int lr = lane & 15, lk = lane >> 4;
  const int sg = (wv & 3) * 16;      // slot subgroup within 64-tile
  const int cg = (wv >> 2) * 32;     // col subgroup within 64

  for (int t = 0; t < 4; ++t){
    int tb = t * 64;
    if (c0 + tb >= cnt) break;
    f32x4 acc[2];
    acc[0] = (f32x4){0.f,0.f,0.f,0.f};
    acc[1] = (f32x4){0.f,0.f,0.f,0.f};
    const float* xrow = x + (size_t)toks[tb + sg + lr] * DIN;
    for (int ks = 0; ks < DIN/32; ++ks){
      s16x8 a = cvt8(xrow + ks*32 + lk*8);
      #pragma unroll
      for (int j = 0; j < 2; ++j){
        int col = cg + j*16 + lr;
        u32 byt = (u32)(col*1024 + (ks*32 + lk*8)*2) ^ (u32)((col & 7) << 4);
        s16x8 b = *(const s16x8*)((char*)lw + byt);
        acc[j] = __builtin_amdgcn_mfma_f32_16x16x32_bf16(a, b, acc[j], 0, 0, 0);
      }
    }
    #pragma unroll
    for (int j = 0; j < 2; ++j){
      int colg = hq*64 + cg + j*16 + lr;
      float bias = b1[e*HDIM + colg];
      #pragma unroll
      for (int r = 0; r < 4; ++r){
        int srow = tb + sg + lk*4 + r;
        if (c0 + srow < cnt){
          float v = acc[j][r] + bias;
          h[(size_t)(off + c0 + srow) * HDIM + colg] = f2b(v > 0.f ? v : 0.f);
        }
      }
    }
  }
}

// ---------------- k_y: y = (h W2e + b2e) * w_slot -> combined ----------------
// PASS 0 (rank-0 slots): combined = v   PASS 1 (rank-1 slots): combined += v
template<int PASS>
__global__ __launch_bounds__(512) void k_y(
    const u16* __restrict__ h, const float* __restrict__ w2, const float* __restrict__ b2,
    const int* __restrict__ offsets, const int* __restrict__ tok_slot,
    const float* __restrict__ w_slot, float* __restrict__ combined)
{
  __shared__ u16 lw[128*256];        // W2e^T quarter [128 cols][256 k], swizzled, 64KB
  __shared__ int   toks[256];
  __shared__ float wts[256];
  const int e = blockIdx.z;
  const int q = blockIdx.y;          // output col quarter
  const int segb = offsets[2*e + PASS];
  const int segc = offsets[2*e + PASS + 1] - segb;
  const int c0 = blockIdx.x * 256;
  if (c0 >= segc) return;
  const int tid = threadIdx.x;
  {
    const float* wsrc = w2 + (size_t)e * HDIM * DOUT + q*128;
    int n4 = (tid & 31) * 4;
    int k0 = tid >> 5;
    for (int it = 0; it < 16; ++it){
      int k = k0 + it*16;
      f32x4 v = *(const f32x4*)(wsrc + (size_t)k * DOUT + n4);
      #pragma unroll
      for (int i = 0; i < 4; ++i){
        int row = n4 + i;
        u32 byt = (u32)(row*512 + k*2) ^ (u32)((row & 7) << 4);
        *(u16*)((char*)lw + byt) = f2b(v[i]);
      }
    }
  }
  if (tid < 256){
    int r = c0 + tid;
    int s = segb + (r < segc ? r : segc - 1);
    toks[tid] = tok_slot[s];
    wts[tid]  = w_slot[s];
  }
  __syncthreads();

  const int wv = tid >> 6, lane = tid & 63;
  const int lr = lane & 15, lk = lane >> 4;
  const int sg = (wv & 3) * 16;
  const int cg = (wv >> 2) * 64;

  for (int t = 0; t < 4; ++t){
    int tb = t * 64;
    if (c0 + tb >= segc) break;
    f32x4 acc[4];
    #pragma unroll
    for (int j = 0; j < 4; ++j) acc[j] = (f32x4){0.f,0.f,0.f,0.f};
    const u16* hrow = h + (size_t)(segb + c0 + tb + sg + lr) * HDIM;
    for (int ks = 0; ks < HDIM/32; ++ks){
      s16x8 a = *(const s16x8*)(hrow + ks*32 + lk*8);
      #pragma unroll
      for (int j = 0; j < 4; ++j){
        int col = cg + j*16 + lr;
        u32 byt = (u32)(col*512 + (ks*32 + lk*8)*2) ^ (u32)((col & 7) << 4);
        s16x8 b = *(const s16x8*)((char*)lw + byt);
        acc[j] = __builtin_amdgcn_mfma_f32_16x16x32_bf16(a, b, acc[j], 0, 0, 0);
      }
    }
    #pragma unroll
    for (int j = 0; j < 4; ++j){
      int colg = q*128 + cg + j*16 + lr;
      float bias = b2[e*DOUT + colg];
      #pragma unroll
      for (int r = 0; r < 4; ++r){
        int srow = tb + sg + lk*4 + r;
        if (c0 + srow < segc){
          int   tok = toks[srow];
          float v   = wts[srow] * (acc[j][r] + bias);
          float* dst = &combined[(size_t)tok * DOUT + colg];
          if (PASS == 0) *dst = v;
          else           *dst += v;
        }
      }
    }
  }
}

// ---------------- vec final: out = A @ W + bias, col-split (NOT in place) ----------------
__global__ __launch_bounds__(256) void k_final(
    const float* __restrict__ A, const float* __restrict__ W,
    const float* __restrict__ bias, float* __restrict__ out)
{
  __shared__ u16 lw[64*512];         // 64KB
  const int tid = threadIdx.x;
  const int r0  = blockIdx.x * 128;
  const int cg0 = blockIdx.y * 64;
  {
    int n4 = (tid >> 4) * 4;         // col 0..60 (swapped map: 4-way writes)
    int k0 = tid & 15;
    for (int it = 0; it < 32; ++it){
      int k = k0 + it*16;
      f32x4 v = *(const f32x4*)(W + (size_t)k * DOUT + cg0 + n4);
      #pragma unroll
      for (int i = 0; i < 4; ++i){
        int row = n4 + i;
        u32 byt = (u32)(row*1024 + k*2) ^ (u32)((row & 7) << 4);
        *(u16*)((char*)lw + byt) = f2b(v[i]);
      }
    }
  }
  __syncthreads();
  const int wv = tid >> 6, lane = tid & 63;
  const int lr = lane & 15, lk = lane >> 4;
  f32x4 acc[2][4];
  #pragma unroll
  for (int i = 0; i < 2; ++i)
    #pragma unroll
    for (int j = 0; j < 4; ++j) acc[i][j] = (f32x4){0.f,0.f,0.f,0.f};
  const float* ar0 = A + (size_t)(r0 + wv*32 + lr) * DOUT;
  const float* ar1 = ar0 + (size_t)16 * DOUT;
  for (int ks = 0; ks < DOUT/32; ++ks){
    s16x8 a0 = cvt8(ar0 + ks*32 + lk*8);
    s16x8 a1 = cvt8(ar1 + ks*32 + lk*8);
    #pragma unroll
    for (int j = 0; j < 4; ++j){
      int col = j*16 + lr;
      u32 byt = (u32)(col*1024 + (ks*32 + lk*8)*2) ^ (u32)((col & 7) << 4);
      s16x8 b = *(const s16x8*)((char*)lw + byt);
      acc[0][j] = __builtin_amdgcn_mfma_f32_16x16x32_bf16(a0, b, acc[0][j], 0, 0, 0);
      acc[1][j] = __builtin_amdgcn_mfma_f32_16x16x32_bf16(a1, b, acc[1][j], 0, 0, 0);
    }
  }
  #pragma unroll
  for (int j = 0; j < 4; ++j){
    int col = cg0 + j*16 + lr;
    float bv = bias[col];
    #pragma unroll
    for (int i = 0; i < 2; ++i)
      #pragma unroll
      for (int r = 0; r < 4; ++r){
        int row = r0 + wv*32 + i*16 + lk*4 + r;
        out[(size_t)row * DOUT + col] = acc[i][j][r] + bv;
      }
  }
}

// ---------------- cls final: self-contained 64-row block, ALL 512 cols, IN PLACE safe ----
// (round-4-verified pattern; staging thread-map swapped for ~4-way writes)
__global__ __launch_bounds__(256) void k_final2(
    const float* __restrict__ A, const float* __restrict__ W,
    const float* __restrict__ bias, float* __restrict__ out)
{
  __shared__ u32 WTu[512][20];
  const int tid  = threadIdx.x;
  const int wave = tid >> 6, lane = tid & 63;
  const int lr = lane & 15, lk = lane >> 4;
  const int rowg = wave >> 1;              // rows rowg*32
  const int colg = wave & 1;               // cols colg*256
  const int kr2 = (tid & 15) * 2;          // 0..30 (swapped)
  const int c32 = tid >> 4;                // 0..15 (swapped)

  f32x4 acc[2][16];
  #pragma unroll
  for (int i = 0; i < 2; ++i)
    #pragma unroll
    for (int j = 0; j < 16; ++j) acc[i][j] = (f32x4){0.f,0.f,0.f,0.f};

  f32x4 r0v[8], r1v[8];
  { const float* src = W + (size_t)kr2 * DOUT + c32*32;
    #pragma unroll
    for (int q = 0; q < 8; ++q){
      r0v[q] = *(const f32x4*)(src + q*4);
      r1v[q] = *(const f32x4*)(src + DOUT + q*4);
    } }

  for (int ks = 0; ks < DOUT/32; ++ks){
    __syncthreads();
    #pragma unroll
    for (int q = 0; q < 8; ++q)
      #pragma unroll
      for (int m = 0; m < 4; ++m)
        WTu[c32*32 + q*4 + m][kr2>>1] = (u32)f2b(r0v[q][m]) | ((u32)f2b(r1v[q][m]) << 16);
    __syncthreads();
    if (ks + 1 < DOUT/32){
      const float* src = W + (size_t)((ks+1)*32 + kr2) * DOUT + c32*32;
      #pragma unroll
      for (int q = 0; q < 8; ++q){
        r0v[q] = *(const f32x4*)(src + q*4);
        r1v[q] = *(const f32x4*)(src + DOUT + q*4);
      }
    }
    s16x8 a[2];
    #pragma unroll
    for (int i = 0; i < 2; ++i){
      int row = blockIdx.x*64 + rowg*32 + i*16 + lr;
      a[i] = cvt8(A + (size_t)row * DOUT + ks*32 + lk*8);
    }
    #pragma unroll
    for (int j = 0; j < 16; ++j){
      int col = colg*256 + j*16 + lr;
      s16x8 bfrag = *(const s16x8*)((const u16*)(&WTu[col][0]) + lk*8);
      #pragma unroll
      for (int i = 0; i < 2; ++i)
        acc[i][j] = __builtin_amdgcn_mfma_f32_16x16x32_bf16(a[i], bfrag, acc[i][j], 0, 0, 0);
    }
  }
  __syncthreads();   // drain ALL A-reads in the block before in-place overwrite

  #pragma unroll
  for (int j = 0; j < 16; ++j){
    int col = colg*256 + j*16 + lr;
    float bv = bias[col];
    #pragma unroll
    for (int i = 0; i < 2; ++i)
      #pragma unroll
      for (int r = 0; r < 4; ++r){
        int row = blockIdx.x*64 + rowg*32 + i*16 + lk*4 + r;
        out[(size_t)row * DOUT + col] = acc[i][j][r] + bv;
      }
  }
}

extern "C" void kernel_launch(void* const* d_in, const int* in_sizes, int n_in,
                              void* d_out, int out_size, void* d_ws, size_t ws_size,
                              hipStream_t stream)
{
  const float* x    = (const float*)d_in[0];
  const float* gw   = (const float*)d_in[1];
  const float* gb   = (const float*)d_in[2];
  const float* w1   = (const float*)d_in[3];
  const float* b1   = (const float*)d_in[4];
  const float* w2   = (const float*)d_in[5];
  const float* b2   = (const float*)d_in[6];
  const float* clsw = (const float*)d_in[7];
  const float* clsb = (const float*)d_in[8];
  const float* vecw = (const float*)d_in[9];
  const float* vecb = (const float*)d_in[10];

  char* base = (char*)d_out;
  float* combined = (float*)base;                               // cls half [0,32M)
  float* vec_out  = (float*)(base + (size_t)NTOK*DOUT*4);       // vec half [32M,64M)
  // scratch inside vec half; fully consumed before k_final(vec) overwrites it:
  u16*   h        = (u16*)  (base + ((size_t)32<<20));          // [32M,48M) bf16[32768][256]
  int*   tok_slot = (int*)  (base + ((size_t)48<<20));
  float* w_slot   = (float*)(base + ((size_t)48<<20) + 131072);
  int*   tke      = (int*)  (base + ((size_t)48<<20) + 262144);
  float* tkw      = (float*)(base + ((size_t)48<<20) + 393216);
  int*   counts   = (int*)  (base + ((size_t)48<<20) + 524288);
  int*   offsets  = (int*)  (base + ((size_t)48<<20) + 524288 + 128);
  int*   cursors  = (int*)  (base + ((size_t)48<<20) + 524288 + 256);

  k_zero<<<dim3(1), dim3(64), 0, stream>>>(counts);
  k_gate<<<dim3(NTOK/4), dim3(256), 0, stream>>>(x, gw, gb, tke, tkw, counts);
  k_scan<<<dim3(1), dim3(64), 0, stream>>>(counts, offsets, cursors);
  k_scatter<<<dim3(NTOK/256), dim3(256), 0, stream>>>(tke, tkw, offsets, cursors,
                                                      tok_slot, w_slot);
  k_h<<<dim3(64, 4, NEXP), dim3(512), 0, stream>>>(x, w1, b1, offsets, tok_slot, h);
  k_y<0><<<dim3(64, 4, NEXP), dim3(512), 0, stream>>>(h, w2, b2, offsets, tok_slot, w_slot, combined);
  k_y<1><<<dim3(64, 4, NEXP), dim3(512), 0, stream>>>(h, w2, b2, offsets, tok_slot, w_slot, combined);
  // vec first: reads combined [0,32M), writes [32M,64M) — disjoint, race-free.
  k_final<<<dim3(NTOK/128, DOUT/64), dim3(256), 0, stream>>>(combined, vecw, vecb, vec_out);
  // cls last: self-contained rows, in-place safe.
  k_final2<<<dim3(NTOK/64), dim3(256), 0, stream>>>(combined, clsw, clsb, combined);
}

// Round 7
// 368.744 us; speedup vs baseline: 2.9670x; 1.7387x over previous
//
#include <hip/hip_runtime.h>

#define NTOK 16384
#define DIN  512
#define DOUT 512
#define HDIM 256
#define NEXP 10
#define NSLOT (2*NTOK)
#define NSEG  (2*NEXP)
#define BM 128
#define BN 128
#define BK 64

typedef unsigned short u16;
typedef unsigned int   u32;
typedef short s16x8 __attribute__((ext_vector_type(8)));
typedef float f32x4 __attribute__((ext_vector_type(4)));

__device__ __forceinline__ u16 f2b(float f){
  union { float f; u32 u; } c; c.f = f;
  u32 r = c.u + 0x7FFFu + ((c.u >> 16) & 1u);
  return (u16)(r >> 16);
}
__device__ __forceinline__ s16x8 cvt8(const float* p){
  f32x4 a = *(const f32x4*)p;
  f32x4 b = *(const f32x4*)(p + 4);
  s16x8 r;
  r[0]=(short)f2b(a[0]); r[1]=(short)f2b(a[1]); r[2]=(short)f2b(a[2]); r[3]=(short)f2b(a[3]);
  r[4]=(short)f2b(b[0]); r[5]=(short)f2b(b[1]); r[6]=(short)f2b(b[2]); r[7]=(short)f2b(b[3]);
  return r;
}

__global__ __launch_bounds__(64) void k_zero(int* counts){
  if (threadIdx.x < NSEG) counts[threadIdx.x] = 0;
}

// ---------------- gating: one wave per token ----------------
__global__ __launch_bounds__(256) void k_gate(
    const float* __restrict__ x, const float* __restrict__ gw, const float* __restrict__ gb,
    int* __restrict__ tke, float* __restrict__ tkw, int* __restrict__ counts)
{
  __shared__ int cnt[NSEG];
  if (threadIdx.x < NSEG) cnt[threadIdx.x] = 0;
  __syncthreads();
  const int wave = threadIdx.x >> 6, lane = threadIdx.x & 63;
  const int token = blockIdx.x * 4 + wave;
  float acc[NEXP];
  #pragma unroll
  for (int e = 0; e < NEXP; ++e) acc[e] = 0.f;
  const float* xr = x + (size_t)token * DIN;
  #pragma unroll
  for (int i = 0; i < DIN/64; ++i){
    int d = lane + 64*i;
    float xv = xr[d];
    const float* g = gw + (size_t)d * NEXP;
    #pragma unroll
    for (int e = 0; e < NEXP; ++e) acc[e] += xv * g[e];
  }
  #pragma unroll
  for (int e = 0; e < NEXP; ++e){
    #pragma unroll
    for (int off = 32; off > 0; off >>= 1) acc[e] += __shfl_xor(acc[e], off, 64);
  }
  if (lane == 0){
    float l[NEXP];
    #pragma unroll
    for (int e = 0; e < NEXP; ++e) l[e] = acc[e] + gb[e];
    int bi = 0; float bv = l[0];
    #pragma unroll
    for (int e = 1; e < NEXP; ++e) if (l[e] > bv){ bv = l[e]; bi = e; }
    int si = -1; float sv = -1e30f;
    #pragma unroll
    for (int e = 0; e < NEXP; ++e) if (e != bi && l[e] > sv){ sv = l[e]; si = e; }
    float w0 = 1.f / (1.f + expf(sv - bv));
    tke[2*token]   = bi;  tke[2*token+1] = si;
    tkw[2*token]   = w0;  tkw[2*token+1] = 1.f - w0;
    atomicAdd(&cnt[2*bi], 1);  atomicAdd(&cnt[2*si+1], 1);
  }
  __syncthreads();
  if (threadIdx.x < NSEG && cnt[threadIdx.x] > 0)
    atomicAdd(&counts[threadIdx.x], cnt[threadIdx.x]);
}

__global__ __launch_bounds__(64) void k_scan(
    const int* __restrict__ counts, int* __restrict__ offsets, int* __restrict__ cursors)
{
  if (threadIdx.x == 0){
    int s = 0;
    for (int i = 0; i < NSEG; ++i){ offsets[i] = s; s += counts[i]; }
    offsets[NSEG] = s;
  }
  if (threadIdx.x < NSEG) cursors[threadIdx.x] = 0;
}

__global__ __launch_bounds__(256) void k_scatter(
    const int* __restrict__ tke, const float* __restrict__ tkw,
    const int* __restrict__ offsets, int* __restrict__ cursors,
    int* __restrict__ tok_slot, float* __restrict__ w_slot)
{
  __shared__ int lcnt[NSEG], lbase[NSEG];
  if (threadIdx.x < NSEG) lcnt[threadIdx.x] = 0;
  __syncthreads();
  int n = blockIdx.x * 256 + threadIdx.x;
  int g0 = 2*tke[2*n], g1 = 2*tke[2*n+1] + 1;
  int p0 = atomicAdd(&lcnt[g0], 1);
  int p1 = atomicAdd(&lcnt[g1], 1);
  __syncthreads();
  if (threadIdx.x < NSEG) lbase[threadIdx.x] = atomicAdd(&cursors[threadIdx.x], lcnt[threadIdx.x]);
  __syncthreads();
  int s0 = offsets[g0] + lbase[g0] + p0;
  int s1 = offsets[g1] + lbase[g1] + p1;
  tok_slot[s0] = n; w_slot[s0] = tkw[2*n];
  tok_slot[s1] = n; w_slot[s1] = tkw[2*n+1];
}

// ---------------- prep: gather routed rows as bf16 ----------------
__global__ __launch_bounds__(256) void k_gather(
    const float* __restrict__ x, const int* __restrict__ tok_slot, u16* __restrict__ xg)
{
  int row  = blockIdx.x * 4 + (threadIdx.x >> 6);
  int lane = threadIdx.x & 63;
  int tok  = tok_slot[row];
  s16x8 v = cvt8(x + (size_t)tok * DIN + lane*8);
  *(s16x8*)(xg + (size_t)row * DIN + lane*8) = v;
}

// ---------------- prep: weight transpose+cvt  in[R][C] f32 -> out[C][R] bf16 ----------------
__global__ __launch_bounds__(256) void k_wt(
    const float* __restrict__ in, u16* __restrict__ out, int R, int C)
{
  __shared__ float tile[32][33];
  const float* src = in + (size_t)blockIdx.z * R * C;
  u16* dst = out + (size_t)blockIdx.z * R * C;
  int cb = blockIdx.x * 32, rb = blockIdx.y * 32;
  int tx = threadIdx.x & 31, ty = threadIdx.x >> 5;
  #pragma unroll
  for (int i = 0; i < 4; ++i)
    tile[ty + i*8][tx] = src[(size_t)(rb + ty + i*8) * C + cb + tx];
  __syncthreads();
  #pragma unroll
  for (int i = 0; i < 4; ++i)
    dst[(size_t)(cb + ty + i*8) * R + rb + tx] = f2b(tile[tx][ty + i*8]);
}

// ---------------- k_h: h = relu(xg W1e + b1e), 128x128 tile, BK=64 dbuf ----------------
__global__ __launch_bounds__(256, 2) void k_h(
    const u16* __restrict__ xg, const u16* __restrict__ w1tb, const float* __restrict__ b1,
    const int* __restrict__ offsets, u16* __restrict__ h)
{
  __shared__ u16 As[2][BM*BK];
  __shared__ u16 Bs[2][BN*BK];
  const int e   = blockIdx.z;
  const int off = offsets[2*e];
  const int cnt = offsets[2*e+2] - off;
  const int c0  = blockIdx.x * BM;
  if (c0 >= cnt) return;
  const int n0  = blockIdx.y * BN;
  const int tid = threadIdx.x;

  const u16* Ag = xg + (size_t)(off + c0) * DIN;
  const u16* Bg = w1tb + ((size_t)e * HDIM + n0) * DIN;

  int crow[4], ckk[4];
  #pragma unroll
  for (int i = 0; i < 4; ++i){
    int c = tid + i*256;
    crow[i] = c >> 3; ckk[i] = (c & 7) * 8;
  }
  s16x8 ra[4], rb[4];
  auto loadregs = [&](int ks){
    #pragma unroll
    for (int i = 0; i < 4; ++i){
      ra[i] = *(const s16x8*)(Ag + (size_t)crow[i]*DIN + ks*BK + ckk[i]);
      rb[i] = *(const s16x8*)(Bg + (size_t)crow[i]*DIN + ks*BK + ckk[i]);
    }
  };
  auto writeregs = [&](int buf){
    #pragma unroll
    for (int i = 0; i < 4; ++i){
      u32 byt = (u32)((crow[i]*BK + ckk[i])*2) ^ ((u32)(crow[i]&7)<<4);
      *(s16x8*)((char*)As[buf] + byt) = ra[i];
      *(s16x8*)((char*)Bs[buf] + byt) = rb[i];
    }
  };

  const int wv = tid >> 6, lane = tid & 63;
  const int lr = lane & 15, lk = lane >> 4;
  const int wr = (wv >> 1) * 64, wc = (wv & 1) * 64;

  f32x4 acc[4][4];
  #pragma unroll
  for (int i = 0; i < 4; ++i)
    #pragma unroll
    for (int j = 0; j < 4; ++j) acc[i][j] = (f32x4){0.f,0.f,0.f,0.f};

  loadregs(0); writeregs(0);
  int cur = 0;
  const int NK = DIN / BK;   // 8
  for (int ks = 0; ks < NK; ++ks){
    __syncthreads();
    if (ks + 1 < NK) loadregs(ks + 1);
    #pragma unroll
    for (int sub = 0; sub < 2; ++sub){
      s16x8 af[4], bf[4];
      #pragma unroll
      for (int g = 0; g < 4; ++g){
        int arow = wr + g*16 + lr;
        u32 ab = (u32)((arow*BK + sub*32 + lk*8)*2) ^ ((u32)(arow&7)<<4);
        af[g] = *(const s16x8*)((char*)As[cur] + ab);
        int bcol = wc + g*16 + lr;
        u32 bb = (u32)((bcol*BK + sub*32 + lk*8)*2) ^ ((u32)(bcol&7)<<4);
        bf[g] = *(const s16x8*)((char*)Bs[cur] + bb);
      }
      #pragma unroll
      for (int i = 0; i < 4; ++i)
        #pragma unroll
        for (int j = 0; j < 4; ++j)
          acc[i][j] = __builtin_amdgcn_mfma_f32_16x16x32_bf16(af[i], bf[j], acc[i][j], 0, 0, 0);
    }
    if (ks + 1 < NK) writeregs(cur ^ 1);
    cur ^= 1;
  }

  #pragma unroll
  for (int j = 0; j < 4; ++j){
    int col = n0 + wc + j*16 + lr;
    float bias = b1[e*HDIM + col];
    #pragma unroll
    for (int i = 0; i < 4; ++i)
      #pragma unroll
      for (int r = 0; r < 4; ++r){
        int row = wr + i*16 + lk*4 + r;
        if (c0 + row < cnt){
          float v = acc[i][j][r] + bias;
          h[(size_t)(off + c0 + row) * HDIM + col] = f2b(v > 0.f ? v : 0.f);
        }
      }
  }
}

// ---------------- k_y: combined(+)= w_slot * (h W2e + b2e), same structure ----------------
template<int PASS>
__global__ __launch_bounds__(256, 2) void k_y(
    const u16* __restrict__ h, const u16* __restrict__ w2tb, const float* __restrict__ b2,
    const int* __restrict__ offsets, const int* __restrict__ tok_slot,
    const float* __restrict__ w_slot, float* __restrict__ combined)
{
  __shared__ u16 As[2][BM*BK];
  __shared__ u16 Bs[2][BN*BK];
  __shared__ int   toks[BM];
  __shared__ float wts[BM];
  const int e    = blockIdx.z;
  const int segb = offsets[2*e + PASS];
  const int segc = offsets[2*e + PASS + 1] - segb;
  const int c0   = blockIdx.x * BM;
  if (c0 >= segc) return;
  const int n0   = blockIdx.y * BN;
  const int tid  = threadIdx.x;

  if (tid < BM){
    int r = c0 + tid;
    int s = segb + (r < segc ? r : segc - 1);
    toks[tid] = tok_slot[s];
    wts[tid]  = w_slot[s];
  }

  const u16* Ag = h + (size_t)(segb + c0) * HDIM;
  const u16* Bg = w2tb + ((size_t)e * DOUT + n0) * HDIM;

  int crow[4], ckk[4];
  #pragma unroll
  for (int i = 0; i < 4; ++i){
    int c = tid + i*256;
    crow[i] = c >> 3; ckk[i] = (c & 7) * 8;
  }
  s16x8 ra[4], rb[4];
  auto loadregs = [&](int ks){
    #pragma unroll
    for (int i = 0; i < 4; ++i){
      ra[i] = *(const s16x8*)(Ag + (size_t)crow[i]*HDIM + ks*BK + ckk[i]);
      rb[i] = *(const s16x8*)(Bg + (size_t)crow[i]*HDIM + ks*BK + ckk[i]);
    }
  };
  auto writeregs = [&](int buf){
    #pragma unroll
    for (int i = 0; i < 4; ++i){
      u32 byt = (u32)((crow[i]*BK + ckk[i])*2) ^ ((u32)(crow[i]&7)<<4);
      *(s16x8*)((char*)As[buf] + byt) = ra[i];
      *(s16x8*)((char*)Bs[buf] + byt) = rb[i];
    }
  };

  const int wv = tid >> 6, lane = tid & 63;
  const int lr = lane & 15, lk = lane >> 4;
  const int wr = (wv >> 1) * 64, wc = (wv & 1) * 64;

  f32x4 acc[4][4];
  #pragma unroll
  for (int i = 0; i < 4; ++i)
    #pragma unroll
    for (int j = 0; j < 4; ++j) acc[i][j] = (f32x4){0.f,0.f,0.f,0.f};

  loadregs(0); writeregs(0);
  int cur = 0;
  const int NK = HDIM / BK;  // 4
  for (int ks = 0; ks < NK; ++ks){
    __syncthreads();
    if (ks + 1 < NK) loadregs(ks + 1);
    #pragma unroll
    for (int sub = 0; sub < 2; ++sub){
      s16x8 af[4], bf[4];
      #pragma unroll
      for (int g = 0; g < 4; ++g){
        int arow = wr + g*16 + lr;
        u32 ab = (u32)((arow*BK + sub*32 + lk*8)*2) ^ ((u32)(arow&7)<<4);
        af[g] = *(const s16x8*)((char*)As[cur] + ab);
        int bcol = wc + g*16 + lr;
        u32 bb = (u32)((bcol*BK + sub*32 + lk*8)*2) ^ ((u32)(bcol&7)<<4);
        bf[g] = *(const s16x8*)((char*)Bs[cur] + bb);
      }
      #pragma unroll
      for (int i = 0; i < 4; ++i)
        #pragma unroll
        for (int j = 0; j < 4; ++j)
          acc[i][j] = __builtin_amdgcn_mfma_f32_16x16x32_bf16(af[i], bf[j], acc[i][j], 0, 0, 0);
    }
    if (ks + 1 < NK) writeregs(cur ^ 1);
    cur ^= 1;
  }

  #pragma unroll
  for (int j = 0; j < 4; ++j){
    int col = n0 + wc + j*16 + lr;
    float bias = b2[e*DOUT + col];
    #pragma unroll
    for (int i = 0; i < 4; ++i)
      #pragma unroll
      for (int r = 0; r < 4; ++r){
        int row = wr + i*16 + lk*4 + r;
        if (c0 + row < segc){
          int tok = toks[row];
          float v = wts[row] * (acc[i][j][r] + bias);
          float* dst = &combined[(size_t)tok * DOUT + col];
          if (PASS == 0) *dst = v;
          else           *dst += v;
        }
      }
  }
}

// ---------------- vec final: col-split, NOT in place (round-6 verified) ----------------
__global__ __launch_bounds__(256) void k_final(
    const float* __restrict__ A, const float* __restrict__ W,
    const float* __restrict__ bias, float* __restrict__ out)
{
  __shared__ u16 lw[64*512];
  const int tid = threadIdx.x;
  const int r0  = blockIdx.x * 128;
  const int cg0 = blockIdx.y * 64;
  {
    int n4 = (tid >> 4) * 4;
    int k0 = tid & 15;
    for (int it = 0; it < 32; ++it){
      int k = k0 + it*16;
      f32x4 v = *(const f32x4*)(W + (size_t)k * DOUT + cg0 + n4);
      #pragma unroll
      for (int i = 0; i < 4; ++i){
        int row = n4 + i;
        u32 byt = (u32)(row*1024 + k*2) ^ (u32)((row & 7) << 4);
        *(u16*)((char*)lw + byt) = f2b(v[i]);
      }
    }
  }
  __syncthreads();
  const int wv = tid >> 6, lane = tid & 63;
  const int lr = lane & 15, lk = lane >> 4;
  f32x4 acc[2][4];
  #pragma unroll
  for (int i = 0; i < 2; ++i)
    #pragma unroll
    for (int j = 0; j < 4; ++j) acc[i][j] = (f32x4){0.f,0.f,0.f,0.f};
  const float* ar0 = A + (size_t)(r0 + wv*32 + lr) * DOUT;
  const float* ar1 = ar0 + (size_t)16 * DOUT;
  for (int ks = 0; ks < DOUT/32; ++ks){
    s16x8 a0 = cvt8(ar0 + ks*32 + lk*8);
    s16x8 a1 = cvt8(ar1 + ks*32 + lk*8);
    #pragma unroll
    for (int j = 0; j < 4; ++j){
      int col = j*16 + lr;
      u32 byt = (u32)(col*1024 + (ks*32 + lk*8)*2) ^ (u32)((col & 7) << 4);
      s16x8 b = *(const s16x8*)((char*)lw + byt);
      acc[0][j] = __builtin_amdgcn_mfma_f32_16x16x32_bf16(a0, b, acc[0][j], 0, 0, 0);
      acc[1][j] = __builtin_amdgcn_mfma_f32_16x16x32_bf16(a1, b, acc[1][j], 0, 0, 0);
    }
  }
  #pragma unroll
  for (int j = 0; j < 4; ++j){
    int col = cg0 + j*16 + lr;
    float bv = bias[col];
    #pragma unroll
    for (int i = 0; i < 2; ++i)
      #pragma unroll
      for (int r = 0; r < 4; ++r){
        int row = r0 + wv*32 + i*16 + lk*4 + r;
        out[(size_t)row * DOUT + col] = acc[i][j][r] + bv;
      }
  }
}

// ---------------- cls final: self-contained 64-row block, in-place safe ----------------
__global__ __launch_bounds__(256) void k_final2(
    const float* __restrict__ A, const float* __restrict__ W,
    const float* __restrict__ bias, float* __restrict__ out)
{
  __shared__ u32 WTu[512][20];
  const int tid  = threadIdx.x;
  const int wave = tid >> 6, lane = tid & 63;
  const int lr = lane & 15, lk = lane >> 4;
  const int rowg = wave >> 1;
  const int colg = wave & 1;
  const int kr2 = (tid & 15) * 2;
  const int c32 = tid >> 4;

  f32x4 acc[2][16];
  #pragma unroll
  for (int i = 0; i < 2; ++i)
    #pragma unroll
    for (int j = 0; j < 16; ++j) acc[i][j] = (f32x4){0.f,0.f,0.f,0.f};

  f32x4 r0v[8], r1v[8];
  { const float* src = W + (size_t)kr2 * DOUT + c32*32;
    #pragma unroll
    for (int q = 0; q < 8; ++q){
      r0v[q] = *(const f32x4*)(src + q*4);
      r1v[q] = *(const f32x4*)(src + DOUT + q*4);
    } }

  for (int ks = 0; ks < DOUT/32; ++ks){
    __syncthreads();
    #pragma unroll
    for (int q = 0; q < 8; ++q)
      #pragma unroll
      for (int m = 0; m < 4; ++m)
        WTu[c32*32 + q*4 + m][kr2>>1] = (u32)f2b(r0v[q][m]) | ((u32)f2b(r1v[q][m]) << 16);
    __syncthreads();
    if (ks + 1 < DOUT/32){
      const float* src = W + (size_t)((ks+1)*32 + kr2) * DOUT + c32*32;
      #pragma unroll
      for (int q = 0; q < 8; ++q){
        r0v[q] = *(const f32x4*)(src + q*4);
        r1v[q] = *(const f32x4*)(src + DOUT + q*4);
      }
    }
    s16x8 a[2];
    #pragma unroll
    for (int i = 0; i < 2; ++i){
      int row = blockIdx.x*64 + rowg*32 + i*16 + lr;
      a[i] = cvt8(A + (size_t)row * DOUT + ks*32 + lk*8);
    }
    #pragma unroll
    for (int j = 0; j < 16; ++j){
      int col = colg*256 + j*16 + lr;
      s16x8 bfrag = *(const s16x8*)((const u16*)(&WTu[col][0]) + lk*8);
      #pragma unroll
      for (int i = 0; i < 2; ++i)
        acc[i][j] = __builtin_amdgcn_mfma_f32_16x16x32_bf16(a[i], bfrag, acc[i][j], 0, 0, 0);
    }
  }
  __syncthreads();

  #pragma unroll
  for (int j = 0; j < 16; ++j){
    int col = colg*256 + j*16 + lr;
    float bv = bias[col];
    #pragma unroll
    for (int i = 0; i < 2; ++i)
      #pragma unroll
      for (int r = 0; r < 4; ++r){
        int row = blockIdx.x*64 + rowg*32 + i*16 + lk*4 + r;
        out[(size_t)row * DOUT + col] = acc[i][j][r] + bv;
      }
  }
}

extern "C" void kernel_launch(void* const* d_in, const int* in_sizes, int n_in,
                              void* d_out, int out_size, void* d_ws, size_t ws_size,
                              hipStream_t stream)
{
  const float* x    = (const float*)d_in[0];
  const float* gw   = (const float*)d_in[1];
  const float* gb   = (const float*)d_in[2];
  const float* w1   = (const float*)d_in[3];
  const float* b1   = (const float*)d_in[4];
  const float* w2   = (const float*)d_in[5];
  const float* b2   = (const float*)d_in[6];
  const float* clsw = (const float*)d_in[7];
  const float* clsb = (const float*)d_in[8];
  const float* vecw = (const float*)d_in[9];
  const float* vecb = (const float*)d_in[10];

  char* base = (char*)d_out;
  float* combined = (float*)base;                               // [0,32M) f32 (written by k_y)
  float* vec_out  = (float*)(base + (size_t)NTOK*DOUT*4);       // [32,64M)
  u16*   xg       = (u16*)base;                                 // [0,32M) bf16 (dead before combined)
  u16*   h        = (u16*)(base + ((size_t)32<<20));            // [32,48M) bf16[32768][256]
  // [48M,48M+128K): pad for harmless A-tile overrun reads past h
  char*  mb       = base + ((size_t)48<<20) + (128<<10);
  int*   tok_slot = (int*)  mb;
  float* w_slot   = (float*)(mb + 131072);
  int*   tke      = (int*)  (mb + 262144);
  float* tkw      = (float*)(mb + 393216);
  int*   counts   = (int*)  (mb + 524288);
  int*   offsets  = (int*)  (mb + 524544);
  int*   cursors  = (int*)  (mb + 524800);
  u16*   w1tb     = (u16*)(base + ((size_t)49<<20));            // bf16 [e][256][512], 2.62M
  u16*   w2tb     = (u16*)(base + ((size_t)52<<20));            // bf16 [e][512][256], 2.62M

  k_zero<<<dim3(1), dim3(64), 0, stream>>>(counts);
  k_gate<<<dim3(NTOK/4), dim3(256), 0, stream>>>(x, gw, gb, tke, tkw, counts);
  k_scan<<<dim3(1), dim3(64), 0, stream>>>(counts, offsets, cursors);
  k_scatter<<<dim3(NTOK/256), dim3(256), 0, stream>>>(tke, tkw, offsets, cursors,
                                                      tok_slot, w_slot);
  k_wt<<<dim3(HDIM/32, DIN/32, NEXP), dim3(256), 0, stream>>>(w1, w1tb, DIN, HDIM);
  k_wt<<<dim3(DOUT/32, HDIM/32, NEXP), dim3(256), 0, stream>>>(w2, w2tb, HDIM, DOUT);
  k_gather<<<dim3(NSLOT/4), dim3(256), 0, stream>>>(x, tok_slot, xg);
  k_h<<<dim3(256, 2, NEXP), dim3(256), 0, stream>>>(xg, w1tb, b1, offsets, h);
  k_y<0><<<dim3(128, 4, NEXP), dim3(256), 0, stream>>>(h, w2tb, b2, offsets, tok_slot, w_slot, combined);
  k_y<1><<<dim3(128, 4, NEXP), dim3(256), 0, stream>>>(h, w2tb, b2, offsets, tok_slot, w_slot, combined);
  // vec: reads combined [0,32M), writes [32,64M) — disjoint.
  k_final<<<dim3(NTOK/128, DOUT/64), dim3(256), 0, stream>>>(combined, vecw, vecb, vec_out);
  // cls last: self-contained rows, in-place.
  k_final2<<<dim3(NTOK/64), dim3(256), 0, stream>>>(combined, clsw, clsb, combined);
}

// Round 8
// 313.176 us; speedup vs baseline: 3.4934x; 1.1774x over previous
//
#include <hip/hip_runtime.h>

#define NTOK 16384
#define DIN  512
#define DOUT 512
#define HDIM 256
#define NEXP 10
#define NSLOT (2*NTOK)
#define NSEG  (2*NEXP)
#define BM 128
#define BN 128
#define BK 64

typedef unsigned short u16;
typedef unsigned int   u32;
typedef short s16x8 __attribute__((ext_vector_type(8)));
typedef float f32x4 __attribute__((ext_vector_type(4)));

__device__ __forceinline__ u16 f2b(float f){
  union { float f; u32 u; } c; c.f = f;
  u32 r = c.u + 0x7FFFu + ((c.u >> 16) & 1u);
  return (u16)(r >> 16);
}
__device__ __forceinline__ s16x8 cvt8(const float* p){
  f32x4 a = *(const f32x4*)p;
  f32x4 b = *(const f32x4*)(p + 4);
  s16x8 r;
  r[0]=(short)f2b(a[0]); r[1]=(short)f2b(a[1]); r[2]=(short)f2b(a[2]); r[3]=(short)f2b(a[3]);
  r[4]=(short)f2b(b[0]); r[5]=(short)f2b(b[1]); r[6]=(short)f2b(b[2]); r[7]=(short)f2b(b[3]);
  return r;
}

__global__ __launch_bounds__(64) void k_zero(int* counts){
  if (threadIdx.x < NSEG) counts[threadIdx.x] = 0;
}

// ---------------- gating: one wave per token ----------------
__global__ __launch_bounds__(256) void k_gate(
    const float* __restrict__ x, const float* __restrict__ gw, const float* __restrict__ gb,
    int* __restrict__ tke, float* __restrict__ tkw, int* __restrict__ counts)
{
  __shared__ int cnt[NSEG];
  if (threadIdx.x < NSEG) cnt[threadIdx.x] = 0;
  __syncthreads();
  const int wave = threadIdx.x >> 6, lane = threadIdx.x & 63;
  const int token = blockIdx.x * 4 + wave;
  float acc[NEXP];
  #pragma unroll
  for (int e = 0; e < NEXP; ++e) acc[e] = 0.f;
  const float* xr = x + (size_t)token * DIN;
  #pragma unroll
  for (int i = 0; i < DIN/64; ++i){
    int d = lane + 64*i;
    float xv = xr[d];
    const float* g = gw + (size_t)d * NEXP;
    #pragma unroll
    for (int e = 0; e < NEXP; ++e) acc[e] += xv * g[e];
  }
  #pragma unroll
  for (int e = 0; e < NEXP; ++e){
    #pragma unroll
    for (int off = 32; off > 0; off >>= 1) acc[e] += __shfl_xor(acc[e], off, 64);
  }
  if (lane == 0){
    float l[NEXP];
    #pragma unroll
    for (int e = 0; e < NEXP; ++e) l[e] = acc[e] + gb[e];
    int bi = 0; float bv = l[0];
    #pragma unroll
    for (int e = 1; e < NEXP; ++e) if (l[e] > bv){ bv = l[e]; bi = e; }
    int si = -1; float sv = -1e30f;
    #pragma unroll
    for (int e = 0; e < NEXP; ++e) if (e != bi && l[e] > sv){ sv = l[e]; si = e; }
    float w0 = 1.f / (1.f + expf(sv - bv));
    tke[2*token]   = bi;  tke[2*token+1] = si;
    tkw[2*token]   = w0;  tkw[2*token+1] = 1.f - w0;
    atomicAdd(&cnt[2*bi], 1);  atomicAdd(&cnt[2*si+1], 1);
  }
  __syncthreads();
  if (threadIdx.x < NSEG && cnt[threadIdx.x] > 0)
    atomicAdd(&counts[threadIdx.x], cnt[threadIdx.x]);
}

__global__ __launch_bounds__(64) void k_scan(
    const int* __restrict__ counts, int* __restrict__ offsets, int* __restrict__ cursors)
{
  if (threadIdx.x == 0){
    int s = 0;
    for (int i = 0; i < NSEG; ++i){ offsets[i] = s; s += counts[i]; }
    offsets[NSEG] = s;
  }
  if (threadIdx.x < NSEG) cursors[threadIdx.x] = 0;
}

__global__ __launch_bounds__(256) void k_scatter(
    const int* __restrict__ tke, const float* __restrict__ tkw,
    const int* __restrict__ offsets, int* __restrict__ cursors,
    int* __restrict__ tok_slot, float* __restrict__ w_slot)
{
  __shared__ int lcnt[NSEG], lbase[NSEG];
  if (threadIdx.x < NSEG) lcnt[threadIdx.x] = 0;
  __syncthreads();
  int n = blockIdx.x * 256 + threadIdx.x;
  int g0 = 2*tke[2*n], g1 = 2*tke[2*n+1] + 1;
  int p0 = atomicAdd(&lcnt[g0], 1);
  int p1 = atomicAdd(&lcnt[g1], 1);
  __syncthreads();
  if (threadIdx.x < NSEG) lbase[threadIdx.x] = atomicAdd(&cursors[threadIdx.x], lcnt[threadIdx.x]);
  __syncthreads();
  int s0 = offsets[g0] + lbase[g0] + p0;
  int s1 = offsets[g1] + lbase[g1] + p1;
  tok_slot[s0] = n; w_slot[s0] = tkw[2*n];
  tok_slot[s1] = n; w_slot[s1] = tkw[2*n+1];
}

// ---------------- prep: weight transpose+cvt  in[R][C] f32 -> out[C][R] bf16 ----------------
__global__ __launch_bounds__(256) void k_wt(
    const float* __restrict__ in, u16* __restrict__ out, int R, int C)
{
  __shared__ float tile[32][33];
  const float* src = in + (size_t)blockIdx.z * R * C;
  u16* dst = out + (size_t)blockIdx.z * R * C;
  int cb = blockIdx.x * 32, rb = blockIdx.y * 32;
  int tx = threadIdx.x & 31, ty = threadIdx.x >> 5;
  #pragma unroll
  for (int i = 0; i < 4; ++i)
    tile[ty + i*8][tx] = src[(size_t)(rb + ty + i*8) * C + cb + tx];
  __syncthreads();
  #pragma unroll
  for (int i = 0; i < 4; ++i)
    dst[(size_t)(cb + ty + i*8) * R + rb + tx] = f2b(tile[tx][ty + i*8]);
}

// ---------------- k_h: h = relu(x[tok] W1e + b1e), gathered A, LDS epilogue ----------------
__global__ __launch_bounds__(256, 2) void k_h(
    const float* __restrict__ x, const u16* __restrict__ w1tb, const float* __restrict__ b1,
    const int* __restrict__ offsets, const int* __restrict__ tok_slot,
    u16* __restrict__ h)
{
  __shared__ __align__(16) char pool[65536];   // As[2]16K | Bs[2]16K ; reused as out-tile
  u16* As = (u16*)pool;
  u16* Bs = (u16*)(pool + 32768);
  __shared__ int toks[BM];
  const int e   = blockIdx.z;
  const int off = offsets[2*e];
  const int cnt = offsets[2*e+2] - off;
  const int c0  = blockIdx.x * BM;
  if (c0 >= cnt) return;
  const int n0  = blockIdx.y * BN;
  const int tid = threadIdx.x;

  if (tid < BM){
    int r = c0 + tid;
    toks[tid] = tok_slot[off + (r < cnt ? r : cnt - 1)];
  }
  __syncthreads();

  const u16* Bg = w1tb + ((size_t)e * HDIM + n0) * DIN;

  int crow[4], ckk[4];
  #pragma unroll
  for (int i = 0; i < 4; ++i){
    int c = tid + i*256;
    crow[i] = c >> 3; ckk[i] = (c & 7) * 8;
  }
  int tokr[4];
  #pragma unroll
  for (int i = 0; i < 4; ++i) tokr[i] = toks[crow[i]];

  s16x8 ra[4], rb[4];
  auto loadregs = [&](int ks){
    #pragma unroll
    for (int i = 0; i < 4; ++i){
      ra[i] = cvt8(x + (size_t)tokr[i]*DIN + ks*BK + ckk[i]);
      rb[i] = *(const s16x8*)(Bg + (size_t)crow[i]*DIN + ks*BK + ckk[i]);
    }
  };
  auto writeregs = [&](int buf){
    #pragma unroll
    for (int i = 0; i < 4; ++i){
      u32 byt = (u32)((crow[i]*BK + ckk[i])*2) ^ ((u32)(crow[i]&7)<<4);
      *(s16x8*)((char*)As + buf*16384 + byt) = ra[i];
      *(s16x8*)((char*)Bs + buf*16384 + byt) = rb[i];
    }
  };

  const int wv = tid >> 6, lane = tid & 63;
  const int lr = lane & 15, lk = lane >> 4;
  const int wr = (wv >> 1) * 64, wc = (wv & 1) * 64;

  f32x4 acc[4][4];
  #pragma unroll
  for (int i = 0; i < 4; ++i)
    #pragma unroll
    for (int j = 0; j < 4; ++j) acc[i][j] = (f32x4){0.f,0.f,0.f,0.f};

  loadregs(0); writeregs(0);
  int cur = 0;
  const int NK = DIN / BK;   // 8
  for (int ks = 0; ks < NK; ++ks){
    __syncthreads();
    if (ks + 1 < NK) loadregs(ks + 1);
    #pragma unroll
    for (int sub = 0; sub < 2; ++sub){
      s16x8 af[4], bf[4];
      #pragma unroll
      for (int g = 0; g < 4; ++g){
        int arow = wr + g*16 + lr;
        u32 ab = (u32)((arow*BK + sub*32 + lk*8)*2) ^ ((u32)(arow&7)<<4);
        af[g] = *(const s16x8*)((char*)As + cur*16384 + ab);
        int bcol = wc + g*16 + lr;
        u32 bb = (u32)((bcol*BK + sub*32 + lk*8)*2) ^ ((u32)(bcol&7)<<4);
        bf[g] = *(const s16x8*)((char*)Bs + cur*16384 + bb);
      }
      #pragma unroll
      for (int i = 0; i < 4; ++i)
        #pragma unroll
        for (int j = 0; j < 4; ++j)
          acc[i][j] = __builtin_amdgcn_mfma_f32_16x16x32_bf16(af[i], bf[j], acc[i][j], 0, 0, 0);
    }
    if (ks + 1 < NK) writeregs(cur ^ 1);
    cur ^= 1;
  }
  __syncthreads();   // all LDS reads done; reuse pool as out-tile

  // epilogue: acc -> LDS (bf16, padded) -> contiguous 128B stores
  u16* outh = (u16*)pool;            // [128][136] u16 = 34816 B
  #pragma unroll
  for (int j = 0; j < 4; ++j){
    int col = wc + j*16 + lr;
    float bias = b1[e*HDIM + n0 + col];
    #pragma unroll
    for (int i = 0; i < 4; ++i)
      #pragma unroll
      for (int r = 0; r < 4; ++r){
        int row = wr + i*16 + lk*4 + r;
        float v = acc[i][j][r] + bias;
        outh[row*136 + col] = f2b(v > 0.f ? v : 0.f);
      }
  }
  __syncthreads();
  {
    int r = tid >> 1, half = tid & 1;
    if (c0 + r < cnt){
      u16* dst = h + (size_t)(off + c0 + r) * HDIM + n0 + half*64;
      const u16* src = outh + r*136 + half*64;
      #pragma unroll
      for (int q = 0; q < 8; ++q)
        *(s16x8*)(dst + q*8) = *(const s16x8*)(src + q*8);
    }
  }
}

// ---------------- k_y: combined(+)= w_slot * (h W2e + b2e), LDS epilogue ----------------
template<int PASS>
__global__ __launch_bounds__(256, 2) void k_y(
    const u16* __restrict__ h, const u16* __restrict__ w2tb, const float* __restrict__ b2,
    const int* __restrict__ offsets, const int* __restrict__ tok_slot,
    const float* __restrict__ w_slot, float* __restrict__ combined)
{
  __shared__ __align__(16) char pool[67584];   // As 16Kx2 | Bs 16Kx2 ; reused: f32[128][132]
  u16* As = (u16*)pool;
  u16* Bs = (u16*)(pool + 32768);
  __shared__ int   toks[BM];
  __shared__ float wts[BM];
  const int e    = blockIdx.z;
  const int segb = offsets[2*e + PASS];
  const int segc = offsets[2*e + PASS + 1] - segb;
  const int c0   = blockIdx.x * BM;
  if (c0 >= segc) return;
  const int n0   = blockIdx.y * BN;
  const int tid  = threadIdx.x;

  if (tid < BM){
    int r = c0 + tid;
    int s = segb + (r < segc ? r : segc - 1);
    toks[tid] = tok_slot[s];
    wts[tid]  = w_slot[s];
  }

  const u16* Ag = h + (size_t)(segb + c0) * HDIM;
  const u16* Bg = w2tb + ((size_t)e * DOUT + n0) * HDIM;

  int crow[4], ckk[4];
  #pragma unroll
  for (int i = 0; i < 4; ++i){
    int c = tid + i*256;
    crow[i] = c >> 3; ckk[i] = (c & 7) * 8;
  }
  s16x8 ra[4], rb[4];
  auto loadregs = [&](int ks){
    #pragma unroll
    for (int i = 0; i < 4; ++i){
      ra[i] = *(const s16x8*)(Ag + (size_t)crow[i]*HDIM + ks*BK + ckk[i]);
      rb[i] = *(const s16x8*)(Bg + (size_t)crow[i]*HDIM + ks*BK + ckk[i]);
    }
  };
  auto writeregs = [&](int buf){
    #pragma unroll
    for (int i = 0; i < 4; ++i){
      u32 byt = (u32)((crow[i]*BK + ckk[i])*2) ^ ((u32)(crow[i]&7)<<4);
      *(s16x8*)((char*)As + buf*16384 + byt) = ra[i];
      *(s16x8*)((char*)Bs + buf*16384 + byt) = rb[i];
    }
  };

  const int wv = tid >> 6, lane = tid & 63;
  const int lr = lane & 15, lk = lane >> 4;
  const int wr = (wv >> 1) * 64, wc = (wv & 1) * 64;

  f32x4 acc[4][4];
  #pragma unroll
  for (int i = 0; i < 4; ++i)
    #pragma unroll
    for (int j = 0; j < 4; ++j) acc[i][j] = (f32x4){0.f,0.f,0.f,0.f};

  loadregs(0); writeregs(0);
  int cur = 0;
  const int NK = HDIM / BK;  // 4
  for (int ks = 0; ks < NK; ++ks){
    __syncthreads();
    if (ks + 1 < NK) loadregs(ks + 1);
    #pragma unroll
    for (int sub = 0; sub < 2; ++sub){
      s16x8 af[4], bf[4];
      #pragma unroll
      for (int g = 0; g < 4; ++g){
        int arow = wr + g*16 + lr;
        u32 ab = (u32)((arow*BK + sub*32 + lk*8)*2) ^ ((u32)(arow&7)<<4);
        af[g] = *(const s16x8*)((char*)As + cur*16384 + ab);
        int bcol = wc + g*16 + lr;
        u32 bb = (u32)((bcol*BK + sub*32 + lk*8)*2) ^ ((u32)(bcol&7)<<4);
        bf[g] = *(const s16x8*)((char*)Bs + cur*16384 + bb);
      }
      #pragma unroll
      for (int i = 0; i < 4; ++i)
        #pragma unroll
        for (int j = 0; j < 4; ++j)
          acc[i][j] = __builtin_amdgcn_mfma_f32_16x16x32_bf16(af[i], bf[j], acc[i][j], 0, 0, 0);
    }
    if (ks + 1 < NK) writeregs(cur ^ 1);
    cur ^= 1;
  }
  __syncthreads();   // LDS reads done; reuse pool

  // epilogue: weighted+biased acc -> LDS f32[128][132] -> contiguous 256B stores
  float* outf = (float*)pool;
  #pragma unroll
  for (int j = 0; j < 4; ++j){
    int col = wc + j*16 + lr;
    float bias = b2[e*DOUT + n0 + col];
    #pragma unroll
    for (int i = 0; i < 4; ++i)
      #pragma unroll
      for (int r = 0; r < 4; ++r){
        int row = wr + i*16 + lk*4 + r;
        outf[row*132 + col] = wts[row] * (acc[i][j][r] + bias);
      }
  }
  __syncthreads();
  {
    int r = tid >> 1, half = tid & 1;
    if (c0 + r < segc){
      float* dst = combined + (size_t)toks[r] * DOUT + n0 + half*64;
      const float* src = outf + r*132 + half*64;
      #pragma unroll
      for (int q = 0; q < 16; ++q){
        f32x4 v = *(const f32x4*)(src + q*4);
        if (PASS == 1) v += *(const f32x4*)(dst + q*4);
        *(f32x4*)(dst + q*4) = v;
      }
    }
  }
}

// ---------------- vec final: col-split, NOT in place (verified) ----------------
__global__ __launch_bounds__(256) void k_final(
    const float* __restrict__ A, const float* __restrict__ W,
    const float* __restrict__ bias, float* __restrict__ out)
{
  __shared__ u16 lw[64*512];
  const int tid = threadIdx.x;
  const int r0  = blockIdx.x * 128;
  const int cg0 = blockIdx.y * 64;
  {
    int n4 = (tid >> 4) * 4;
    int k0 = tid & 15;
    for (int it = 0; it < 32; ++it){
      int k = k0 + it*16;
      f32x4 v = *(const f32x4*)(W + (size_t)k * DOUT + cg0 + n4);
      #pragma unroll
      for (int i = 0; i < 4; ++i){
        int row = n4 + i;
        u32 byt = (u32)(row*1024 + k*2) ^ (u32)((row & 7) << 4);
        *(u16*)((char*)lw + byt) = f2b(v[i]);
      }
    }
  }
  __syncthreads();
  const int wv = tid >> 6, lane = tid & 63;
  const int lr = lane & 15, lk = lane >> 4;
  f32x4 acc[2][4];
  #pragma unroll
  for (int i = 0; i < 2; ++i)
    #pragma unroll
    for (int j = 0; j < 4; ++j) acc[i][j] = (f32x4){0.f,0.f,0.f,0.f};
  const float* ar0 = A + (size_t)(r0 + wv*32 + lr) * DOUT;
  const float* ar1 = ar0 + (size_t)16 * DOUT;
  for (int ks = 0; ks < DOUT/32; ++ks){
    s16x8 a0 = cvt8(ar0 + ks*32 + lk*8);
    s16x8 a1 = cvt8(ar1 + ks*32 + lk*8);
    #pragma unroll
    for (int j = 0; j < 4; ++j){
      int col = j*16 + lr;
      u32 byt = (u32)(col*1024 + (ks*32 + lk*8)*2) ^ (u32)((col & 7) << 4);
      s16x8 b = *(const s16x8*)((char*)lw + byt);
      acc[0][j] = __builtin_amdgcn_mfma_f32_16x16x32_bf16(a0, b, acc[0][j], 0, 0, 0);
      acc[1][j] = __builtin_amdgcn_mfma_f32_16x16x32_bf16(a1, b, acc[1][j], 0, 0, 0);
    }
  }
  #pragma unroll
  for (int j = 0; j < 4; ++j){
    int col = cg0 + j*16 + lr;
    float bv = bias[col];
    #pragma unroll
    for (int i = 0; i < 2; ++i)
      #pragma unroll
      for (int r = 0; r < 4; ++r){
        int row = r0 + wv*32 + i*16 + lk*4 + r;
        out[(size_t)row * DOUT + col] = acc[i][j][r] + bv;
      }
  }
}

// ---------------- cls final: self-contained 64-row block, in-place safe ----------------
__global__ __launch_bounds__(256) void k_final2(
    const float* __restrict__ A, const float* __restrict__ W,
    const float* __restrict__ bias, float* __restrict__ out)
{
  __shared__ u32 WTu[512][20];
  const int tid  = threadIdx.x;
  const int wave = tid >> 6, lane = tid & 63;
  const int lr = lane & 15, lk = lane >> 4;
  const int rowg = wave >> 1;
  const int colg = wave & 1;
  const int kr2 = (tid & 15) * 2;
  const int c32 = tid >> 4;

  f32x4 acc[2][16];
  #pragma unroll
  for (int i = 0; i < 2; ++i)
    #pragma unroll
    for (int j = 0; j < 16; ++j) acc[i][j] = (f32x4){0.f,0.f,0.f,0.f};

  f32x4 r0v[8], r1v[8];
  { const float* src = W + (size_t)kr2 * DOUT + c32*32;
    #pragma unroll
    for (int q = 0; q < 8; ++q){
      r0v[q] = *(const f32x4*)(src + q*4);
      r1v[q] = *(const f32x4*)(src + DOUT + q*4);
    } }

  for (int ks = 0; ks < DOUT/32; ++ks){
    __syncthreads();
    #pragma unroll
    for (int q = 0; q < 8; ++q)
      #pragma unroll
      for (int m = 0; m < 4; ++m)
        WTu[c32*32 + q*4 + m][kr2>>1] = (u32)f2b(r0v[q][m]) | ((u32)f2b(r1v[q][m]) << 16);
    __syncthreads();
    if (ks + 1 < DOUT/32){
      const float* src = W + (size_t)((ks+1)*32 + kr2) * DOUT + c32*32;
      #pragma unroll
      for (int q = 0; q < 8; ++q){
        r0v[q] = *(const f32x4*)(src + q*4);
        r1v[q] = *(const f32x4*)(src + DOUT + q*4);
      }
    }
    s16x8 a[2];
    #pragma unroll
    for (int i = 0; i < 2; ++i){
      int row = blockIdx.x*64 + rowg*32 + i*16 + lr;
      a[i] = cvt8(A + (size_t)row * DOUT + ks*32 + lk*8);
    }
    #pragma unroll
    for (int j = 0; j < 16; ++j){
      int col = colg*256 + j*16 + lr;
      s16x8 bfrag = *(const s16x8*)((const u16*)(&WTu[col][0]) + lk*8);
      #pragma unroll
      for (int i = 0; i < 2; ++i)
        acc[i][j] = __builtin_amdgcn_mfma_f32_16x16x32_bf16(a[i], bfrag, acc[i][j], 0, 0, 0);
    }
  }
  __syncthreads();

  #pragma unroll
  for (int j = 0; j < 16; ++j){
    int col = colg*256 + j*16 + lr;
    float bv = bias[col];
    #pragma unroll
    for (int i = 0; i < 2; ++i)
      #pragma unroll
      for (int r = 0; r < 4; ++r){
        int row = blockIdx.x*64 + rowg*32 + i*16 + lk*4 + r;
        out[(size_t)row * DOUT + col] = acc[i][j][r] + bv;
      }
  }
}

extern "C" void kernel_launch(void* const* d_in, const int* in_sizes, int n_in,
                              void* d_out, int out_size, void* d_ws, size_t ws_size,
                              hipStream_t stream)
{
  const float* x    = (const float*)d_in[0];
  const float* gw   = (const float*)d_in[1];
  const float* gb   = (const float*)d_in[2];
  const float* w1   = (const float*)d_in[3];
  const float* b1   = (const float*)d_in[4];
  const float* w2   = (const float*)d_in[5];
  const float* b2   = (const float*)d_in[6];
  const float* clsw = (const float*)d_in[7];
  const float* clsb = (const float*)d_in[8];
  const float* vecw = (const float*)d_in[9];
  const float* vecb = (const float*)d_in[10];

  char* base = (char*)d_out;
  float* combined = (float*)base;                               // [0,32Mi) f32
  float* vec_out  = (float*)(base + (size_t)NTOK*DOUT*4);       // [32,64Mi)
  u16*   h        = (u16*)(base + ((size_t)32<<20));            // [32,48Mi) bf16[32768][256]
  // [48Mi,+128K): pad for harmless A-tile overrun reads past h
  char*  mb       = base + ((size_t)48<<20) + (128<<10);
  int*   tok_slot = (int*)  mb;
  float* w_slot   = (float*)(mb + 131072);
  int*   tke      = (int*)  (mb + 262144);
  float* tkw      = (float*)(mb + 393216);
  int*   counts   = (int*)  (mb + 524288);
  int*   offsets  = (int*)  (mb + 524544);
  int*   cursors  = (int*)  (mb + 524800);
  u16*   w1tb     = (u16*)(base + ((size_t)49<<20));            // bf16 [e][256][512]
  u16*   w2tb     = (u16*)(base + ((size_t)52<<20));            // bf16 [e][512][256]

  k_zero<<<dim3(1), dim3(64), 0, stream>>>(counts);
  k_gate<<<dim3(NTOK/4), dim3(256), 0, stream>>>(x, gw, gb, tke, tkw, counts);
  k_scan<<<dim3(1), dim3(64), 0, stream>>>(counts, offsets, cursors);
  k_scatter<<<dim3(NTOK/256), dim3(256), 0, stream>>>(tke, tkw, offsets, cursors,
                                                      tok_slot, w_slot);
  k_wt<<<dim3(HDIM/32, DIN/32, NEXP), dim3(256), 0, stream>>>(w1, w1tb, DIN, HDIM);
  k_wt<<<dim3(DOUT/32, HDIM/32, NEXP), dim3(256), 0, stream>>>(w2, w2tb, HDIM, DOUT);
  k_h<<<dim3(256, 2, NEXP), dim3(256), 0, stream>>>(x, w1tb, b1, offsets, tok_slot, h);
  k_y<0><<<dim3(128, 4, NEXP), dim3(256), 0, stream>>>(h, w2tb, b2, offsets, tok_slot, w_slot, combined);
  k_y<1><<<dim3(128, 4, NEXP), dim3(256), 0, stream>>>(h, w2tb, b2, offsets, tok_slot, w_slot, combined);
  k_final<<<dim3(NTOK/128, DOUT/64), dim3(256), 0, stream>>>(combined, vecw, vecb, vec_out);
  k_final2<<<dim3(NTOK/64), dim3(256), 0, stream>>>(combined, clsw, clsb, combined);
}

// Round 9
// 282.618 us; speedup vs baseline: 3.8712x; 1.1081x over previous
//
#include <hip/hip_runtime.h>

#define NTOK 16384
#define DIN  512
#define DOUT 512
#define HDIM 256
#define NEXP 10
#define NSLOT (2*NTOK)
#define NSEG  (2*NEXP)
#define BM 128
#define BN 128
#define BK 64

typedef unsigned short u16;
typedef unsigned int   u32;
typedef short s16x8 __attribute__((ext_vector_type(8)));
typedef float f32x4 __attribute__((ext_vector_type(4)));

__device__ __forceinline__ u16 f2b(float f){
  union { float f; u32 u; } c; c.f = f;
  u32 r = c.u + 0x7FFFu + ((c.u >> 16) & 1u);
  return (u16)(r >> 16);
}
__device__ __forceinline__ u32 pk2(float lo, float hi){
  return (u32)f2b(lo) | ((u32)f2b(hi) << 16);
}
__device__ __forceinline__ s16x8 cvt8(const float* p){
  f32x4 a = *(const f32x4*)p;
  f32x4 b = *(const f32x4*)(p + 4);
  s16x8 r;
  r[0]=(short)f2b(a[0]); r[1]=(short)f2b(a[1]); r[2]=(short)f2b(a[2]); r[3]=(short)f2b(a[3]);
  r[4]=(short)f2b(b[0]); r[5]=(short)f2b(b[1]); r[6]=(short)f2b(b[2]); r[7]=(short)f2b(b[3]);
  return r;
}

__global__ __launch_bounds__(64) void k_zero(int* counts){
  if (threadIdx.x < NSEG) counts[threadIdx.x] = 0;
}

// ---------------- gating: one wave per token ----------------
__global__ __launch_bounds__(256) void k_gate(
    const float* __restrict__ x, const float* __restrict__ gw, const float* __restrict__ gb,
    int* __restrict__ tke, float* __restrict__ tkw, int* __restrict__ counts)
{
  __shared__ int cnt[NSEG];
  if (threadIdx.x < NSEG) cnt[threadIdx.x] = 0;
  __syncthreads();
  const int wave = threadIdx.x >> 6, lane = threadIdx.x & 63;
  const int token = blockIdx.x * 4 + wave;
  float acc[NEXP];
  #pragma unroll
  for (int e = 0; e < NEXP; ++e) acc[e] = 0.f;
  const float* xr = x + (size_t)token * DIN;
  #pragma unroll
  for (int i = 0; i < DIN/64; ++i){
    int d = lane + 64*i;
    float xv = xr[d];
    const float* g = gw + (size_t)d * NEXP;
    #pragma unroll
    for (int e = 0; e < NEXP; ++e) acc[e] += xv * g[e];
  }
  #pragma unroll
  for (int e = 0; e < NEXP; ++e){
    #pragma unroll
    for (int off = 32; off > 0; off >>= 1) acc[e] += __shfl_xor(acc[e], off, 64);
  }
  if (lane == 0){
    float l[NEXP];
    #pragma unroll
    for (int e = 0; e < NEXP; ++e) l[e] = acc[e] + gb[e];
    int bi = 0; float bv = l[0];
    #pragma unroll
    for (int e = 1; e < NEXP; ++e) if (l[e] > bv){ bv = l[e]; bi = e; }
    int si = -1; float sv = -1e30f;
    #pragma unroll
    for (int e = 0; e < NEXP; ++e) if (e != bi && l[e] > sv){ sv = l[e]; si = e; }
    float w0 = 1.f / (1.f + expf(sv - bv));
    tke[2*token]   = bi;  tke[2*token+1] = si;
    tkw[2*token]   = w0;  tkw[2*token+1] = 1.f - w0;
    atomicAdd(&cnt[2*bi], 1);  atomicAdd(&cnt[2*si+1], 1);
  }
  __syncthreads();
  if (threadIdx.x < NSEG && cnt[threadIdx.x] > 0)
    atomicAdd(&counts[threadIdx.x], cnt[threadIdx.x]);
}

__global__ __launch_bounds__(64) void k_scan(
    const int* __restrict__ counts, int* __restrict__ offsets, int* __restrict__ cursors)
{
  if (threadIdx.x == 0){
    int s = 0;
    for (int i = 0; i < NSEG; ++i){ offsets[i] = s; s += counts[i]; }
    offsets[NSEG] = s;
  }
  if (threadIdx.x < NSEG) cursors[threadIdx.x] = 0;
}

__global__ __launch_bounds__(256) void k_scatter(
    const int* __restrict__ tke, const float* __restrict__ tkw,
    const int* __restrict__ offsets, int* __restrict__ cursors,
    int* __restrict__ tok_slot, float* __restrict__ w_slot)
{
  __shared__ int lcnt[NSEG], lbase[NSEG];
  if (threadIdx.x < NSEG) lcnt[threadIdx.x] = 0;
  __syncthreads();
  int n = blockIdx.x * 256 + threadIdx.x;
  int g0 = 2*tke[2*n], g1 = 2*tke[2*n+1] + 1;
  int p0 = atomicAdd(&lcnt[g0], 1);
  int p1 = atomicAdd(&lcnt[g1], 1);
  __syncthreads();
  if (threadIdx.x < NSEG) lbase[threadIdx.x] = atomicAdd(&cursors[threadIdx.x], lcnt[threadIdx.x]);
  __syncthreads();
  int s0 = offsets[g0] + lbase[g0] + p0;
  int s1 = offsets[g1] + lbase[g1] + p1;
  tok_slot[s0] = n; w_slot[s0] = tkw[2*n];
  tok_slot[s1] = n; w_slot[s1] = tkw[2*n+1];
}

// ---------------- prep: weight transpose+cvt  in[R][C] f32 -> out[C][R] bf16 ----------------
__global__ __launch_bounds__(256) void k_wt(
    const float* __restrict__ in, u16* __restrict__ out, int R, int C)
{
  __shared__ float tile[32][33];
  const float* src = in + (size_t)blockIdx.z * R * C;
  u16* dst = out + (size_t)blockIdx.z * R * C;
  int cb = blockIdx.x * 32, rb = blockIdx.y * 32;
  int tx = threadIdx.x & 31, ty = threadIdx.x >> 5;
  #pragma unroll
  for (int i = 0; i < 4; ++i)
    tile[ty + i*8][tx] = src[(size_t)(rb + ty + i*8) * C + cb + tx];
  __syncthreads();
  #pragma unroll
  for (int i = 0; i < 4; ++i)
    dst[(size_t)(cb + ty + i*8) * R + rb + tx] = f2b(tile[tx][ty + i*8]);
}

// ---------------- k_h: h = relu(x[tok] W1e + b1e), gathered A, LDS epilogue ----------------
__global__ __launch_bounds__(256, 2) void k_h(
    const float* __restrict__ x, const u16* __restrict__ w1tb, const float* __restrict__ b1,
    const int* __restrict__ offsets, const int* __restrict__ tok_slot,
    u16* __restrict__ h)
{
  __shared__ __align__(16) char pool[65536];
  u16* As = (u16*)pool;
  u16* Bs = (u16*)(pool + 32768);
  __shared__ int toks[BM];
  const int e   = blockIdx.z;
  const int off = offsets[2*e];
  const int cnt = offsets[2*e+2] - off;
  const int c0  = blockIdx.x * BM;
  if (c0 >= cnt) return;
  const int n0  = blockIdx.y * BN;
  const int tid = threadIdx.x;

  if (tid < BM){
    int r = c0 + tid;
    toks[tid] = tok_slot[off + (r < cnt ? r : cnt - 1)];
  }
  __syncthreads();

  const u16* Bg = w1tb + ((size_t)e * HDIM + n0) * DIN;

  int crow[4], ckk[4];
  #pragma unroll
  for (int i = 0; i < 4; ++i){
    int c = tid + i*256;
    crow[i] = c >> 3; ckk[i] = (c & 7) * 8;
  }
  int tokr[4];
  #pragma unroll
  for (int i = 0; i < 4; ++i) tokr[i] = toks[crow[i]];

  s16x8 ra[4], rb[4];
  auto loadregs = [&](int ks){
    #pragma unroll
    for (int i = 0; i < 4; ++i){
      ra[i] = cvt8(x + (size_t)tokr[i]*DIN + ks*BK + ckk[i]);
      rb[i] = *(const s16x8*)(Bg + (size_t)crow[i]*DIN + ks*BK + ckk[i]);
    }
  };
  auto writeregs = [&](int buf){
    #pragma unroll
    for (int i = 0; i < 4; ++i){
      u32 byt = (u32)((crow[i]*BK + ckk[i])*2) ^ ((u32)(crow[i]&7)<<4);
      *(s16x8*)((char*)As + buf*16384 + byt) = ra[i];
      *(s16x8*)((char*)Bs + buf*16384 + byt) = rb[i];
    }
  };

  const int wv = tid >> 6, lane = tid & 63;
  const int lr = lane & 15, lk = lane >> 4;
  const int wr = (wv >> 1) * 64, wc = (wv & 1) * 64;

  f32x4 acc[4][4];
  #pragma unroll
  for (int i = 0; i < 4; ++i)
    #pragma unroll
    for (int j = 0; j < 4; ++j) acc[i][j] = (f32x4){0.f,0.f,0.f,0.f};

  loadregs(0); writeregs(0);
  int cur = 0;
  const int NK = DIN / BK;
  for (int ks = 0; ks < NK; ++ks){
    __syncthreads();
    if (ks + 1 < NK) loadregs(ks + 1);
    #pragma unroll
    for (int sub = 0; sub < 2; ++sub){
      s16x8 af[4], bf[4];
      #pragma unroll
      for (int g = 0; g < 4; ++g){
        int arow = wr + g*16 + lr;
        u32 ab = (u32)((arow*BK + sub*32 + lk*8)*2) ^ ((u32)(arow&7)<<4);
        af[g] = *(const s16x8*)((char*)As + cur*16384 + ab);
        int bcol = wc + g*16 + lr;
        u32 bb = (u32)((bcol*BK + sub*32 + lk*8)*2) ^ ((u32)(bcol&7)<<4);
        bf[g] = *(const s16x8*)((char*)Bs + cur*16384 + bb);
      }
      #pragma unroll
      for (int i = 0; i < 4; ++i)
        #pragma unroll
        for (int j = 0; j < 4; ++j)
          acc[i][j] = __builtin_amdgcn_mfma_f32_16x16x32_bf16(af[i], bf[j], acc[i][j], 0, 0, 0);
    }
    if (ks + 1 < NK) writeregs(cur ^ 1);
    cur ^= 1;
  }
  __syncthreads();

  u16* outh = (u16*)pool;            // [128][136]
  #pragma unroll
  for (int j = 0; j < 4; ++j){
    int col = wc + j*16 + lr;
    float bias = b1[e*HDIM + n0 + col];
    #pragma unroll
    for (int i = 0; i < 4; ++i)
      #pragma unroll
      for (int r = 0; r < 4; ++r){
        int row = wr + i*16 + lk*4 + r;
        float v = acc[i][j][r] + bias;
        outh[row*136 + col] = f2b(v > 0.f ? v : 0.f);
      }
  }
  __syncthreads();
  {
    int r = tid >> 1, half = tid & 1;
    if (c0 + r < cnt){
      u16* dst = h + (size_t)(off + c0 + r) * HDIM + n0 + half*64;
      const u16* src = outh + r*136 + half*64;
      #pragma unroll
      for (int q = 0; q < 8; ++q)
        *(s16x8*)(dst + q*8) = *(const s16x8*)(src + q*8);
    }
  }
}

// ---------------- k_y: combined(+)= w_slot * (h W2e + b2e), LDS epilogue ----------------
template<int PASS>
__global__ __launch_bounds__(256, 2) void k_y(
    const u16* __restrict__ h, const u16* __restrict__ w2tb, const float* __restrict__ b2,
    const int* __restrict__ offsets, const int* __restrict__ tok_slot,
    const float* __restrict__ w_slot, float* __restrict__ combined)
{
  __shared__ __align__(16) char pool[67584];
  u16* As = (u16*)pool;
  u16* Bs = (u16*)(pool + 32768);
  __shared__ int   toks[BM];
  __shared__ float wts[BM];
  const int e    = blockIdx.z;
  const int segb = offsets[2*e + PASS];
  const int segc = offsets[2*e + PASS + 1] - segb;
  const int c0   = blockIdx.x * BM;
  if (c0 >= segc) return;
  const int n0   = blockIdx.y * BN;
  const int tid  = threadIdx.x;

  if (tid < BM){
    int r = c0 + tid;
    int s = segb + (r < segc ? r : segc - 1);
    toks[tid] = tok_slot[s];
    wts[tid]  = w_slot[s];
  }

  const u16* Ag = h + (size_t)(segb + c0) * HDIM;
  const u16* Bg = w2tb + ((size_t)e * DOUT + n0) * HDIM;

  int crow[4], ckk[4];
  #pragma unroll
  for (int i = 0; i < 4; ++i){
    int c = tid + i*256;
    crow[i] = c >> 3; ckk[i] = (c & 7) * 8;
  }
  s16x8 ra[4], rb[4];
  auto loadregs = [&](int ks){
    #pragma unroll
    for (int i = 0; i < 4; ++i){
      ra[i] = *(const s16x8*)(Ag + (size_t)crow[i]*HDIM + ks*BK + ckk[i]);
      rb[i] = *(const s16x8*)(Bg + (size_t)crow[i]*HDIM + ks*BK + ckk[i]);
    }
  };
  auto writeregs = [&](int buf){
    #pragma unroll
    for (int i = 0; i < 4; ++i){
      u32 byt = (u32)((crow[i]*BK + ckk[i])*2) ^ ((u32)(crow[i]&7)<<4);
      *(s16x8*)((char*)As + buf*16384 + byt) = ra[i];
      *(s16x8*)((char*)Bs + buf*16384 + byt) = rb[i];
    }
  };

  const int wv = tid >> 6, lane = tid & 63;
  const int lr = lane & 15, lk = lane >> 4;
  const int wr = (wv >> 1) * 64, wc = (wv & 1) * 64;

  f32x4 acc[4][4];
  #pragma unroll
  for (int i = 0; i < 4; ++i)
    #pragma unroll
    for (int j = 0; j < 4; ++j) acc[i][j] = (f32x4){0.f,0.f,0.f,0.f};

  loadregs(0); writeregs(0);
  int cur = 0;
  const int NK = HDIM / BK;
  for (int ks = 0; ks < NK; ++ks){
    __syncthreads();
    if (ks + 1 < NK) loadregs(ks + 1);
    #pragma unroll
    for (int sub = 0; sub < 2; ++sub){
      s16x8 af[4], bf[4];
      #pragma unroll
      for (int g = 0; g < 4; ++g){
        int arow = wr + g*16 + lr;
        u32 ab = (u32)((arow*BK + sub*32 + lk*8)*2) ^ ((u32)(arow&7)<<4);
        af[g] = *(const s16x8*)((char*)As + cur*16384 + ab);
        int bcol = wc + g*16 + lr;
        u32 bb = (u32)((bcol*BK + sub*32 + lk*8)*2) ^ ((u32)(bcol&7)<<4);
        bf[g] = *(const s16x8*)((char*)Bs + cur*16384 + bb);
      }
      #pragma unroll
      for (int i = 0; i < 4; ++i)
        #pragma unroll
        for (int j = 0; j < 4; ++j)
          acc[i][j] = __builtin_amdgcn_mfma_f32_16x16x32_bf16(af[i], bf[j], acc[i][j], 0, 0, 0);
    }
    if (ks + 1 < NK) writeregs(cur ^ 1);
    cur ^= 1;
  }
  __syncthreads();

  float* outf = (float*)pool;        // [128][132]
  #pragma unroll
  for (int j = 0; j < 4; ++j){
    int col = wc + j*16 + lr;
    float bias = b2[e*DOUT + n0 + col];
    #pragma unroll
    for (int i = 0; i < 4; ++i)
      #pragma unroll
      for (int r = 0; r < 4; ++r){
        int row = wr + i*16 + lk*4 + r;
        outf[row*132 + col] = wts[row] * (acc[i][j][r] + bias);
      }
  }
  __syncthreads();
  {
    int r = tid >> 1, half = tid & 1;
    if (c0 + r < segc){
      float* dst = combined + (size_t)toks[r] * DOUT + n0 + half*64;
      const float* src = outf + r*132 + half*64;
      #pragma unroll
      for (int q = 0; q < 16; ++q){
        f32x4 v = *(const f32x4*)(src + q*4);
        if (PASS == 1) v += *(const f32x4*)(dst + q*4);
        *(f32x4*)(dst + q*4) = v;
      }
    }
  }
}

// ---------------- merged final: per 64-row block, cls (in place) + vec ----------------
// A = combined rows (read fully before in-place overwrite; self-contained).
// W tiles staged from ORIGINAL f32 weights (d_in, never clobbered) per BK=32 step.
// LDS rows 80B (bank period 8 -> 2-way = free). 8 waves, wave tile 64x64 per output.
__global__ __launch_bounds__(512, 2) void k_fin(
    const float* __restrict__ A, const float* __restrict__ Wc, const float* __restrict__ Wv,
    const float* __restrict__ bc, const float* __restrict__ bv,
    float* __restrict__ outc, float* __restrict__ outv)
{
  __shared__ __align__(16) char lds[87040];   // A 64x80B | Bc 512x80B | Bv 512x80B
  char* Ab = lds;
  char* Bc = lds + 5120;
  char* Bv = lds + 5120 + 40960;
  const int tid = threadIdx.x;
  const int r0  = blockIdx.x * 64;

  // staging maps
  const int ar  = tid >> 3;          // A row 0..63
  const int akk = (tid & 7) * 4;     // A k-chunk (4 floats)
  int bc4[4], bkp[4];
  #pragma unroll
  for (int u = 0; u < 4; ++u){
    int idx = tid + u*512;
    bc4[u] = idx >> 4;               // col group of 4 (0..127)
    bkp[u] = idx & 15;               // k-pair (0..15)
  }

  u32 apk0, apk1;
  u32 cpk[4][4], vpk[4][4];
  auto loadregs = [&](int ks){
    f32x4 av = *(const f32x4*)(A + (size_t)(r0 + ar) * DOUT + ks*32 + akk);
    apk0 = pk2(av[0], av[1]); apk1 = pk2(av[2], av[3]);
    #pragma unroll
    for (int u = 0; u < 4; ++u){
      const float* p0 = Wc + (size_t)(ks*32 + 2*bkp[u]) * DOUT + bc4[u]*4;
      f32x4 v0 = *(const f32x4*)p0;
      f32x4 v1 = *(const f32x4*)(p0 + DOUT);
      #pragma unroll
      for (int m = 0; m < 4; ++m) cpk[u][m] = pk2(v0[m], v1[m]);
      const float* q0 = Wv + (size_t)(ks*32 + 2*bkp[u]) * DOUT + bc4[u]*4;
      f32x4 w0 = *(const f32x4*)q0;
      f32x4 w1 = *(const f32x4*)(q0 + DOUT);
      #pragma unroll
      for (int m = 0; m < 4; ++m) vpk[u][m] = pk2(w0[m], w1[m]);
    }
  };
  auto writeregs = [&](){
    *(u32*)(Ab + ar*80 + akk*2)     = apk0;
    *(u32*)(Ab + ar*80 + akk*2 + 4) = apk1;
    #pragma unroll
    for (int u = 0; u < 4; ++u)
      #pragma unroll
      for (int m = 0; m < 4; ++m){
        int col = bc4[u]*4 + m;
        *(u32*)(Bc + col*80 + bkp[u]*4) = cpk[u][m];
        *(u32*)(Bv + col*80 + bkp[u]*4) = vpk[u][m];
      }
  };

  const int wv = tid >> 6, lane = tid & 63;
  const int lr = lane & 15, lk = lane >> 4;
  const int wc = wv * 64;

  f32x4 accC[4][4], accV[4][4];
  #pragma unroll
  for (int i = 0; i < 4; ++i)
    #pragma unroll
    for (int j = 0; j < 4; ++j){
      accC[i][j] = (f32x4){0.f,0.f,0.f,0.f};
      accV[i][j] = (f32x4){0.f,0.f,0.f,0.f};
    }

  loadregs(0); writeregs();
  const int NK = DOUT / 32;   // 16
  for (int ks = 0; ks < NK; ++ks){
    __syncthreads();
    if (ks + 1 < NK) loadregs(ks + 1);
    s16x8 af[4], bcf[4], bvf[4];
    #pragma unroll
    for (int g = 0; g < 4; ++g){
      af[g]  = *(const s16x8*)(Ab + (g*16 + lr)*80 + lk*16);
      int col = wc + g*16 + lr;
      bcf[g] = *(const s16x8*)(Bc + col*80 + lk*16);
      bvf[g] = *(const s16x8*)(Bv + col*80 + lk*16);
    }
    #pragma unroll
    for (int i = 0; i < 4; ++i)
      #pragma unroll
      for (int j = 0; j < 4; ++j){
        accC[i][j] = __builtin_amdgcn_mfma_f32_16x16x32_bf16(af[i], bcf[j], accC[i][j], 0, 0, 0);
        accV[i][j] = __builtin_amdgcn_mfma_f32_16x16x32_bf16(af[i], bvf[j], accV[i][j], 0, 0, 0);
      }
    __syncthreads();
    if (ks + 1 < NK) writeregs();
  }
  // all A global loads completed (vmcnt drained at last barrier) -> in-place safe

  #pragma unroll
  for (int j = 0; j < 4; ++j){
    int col = wc + j*16 + lr;
    float bC = bc[col], bV = bv[col];
    #pragma unroll
    for (int i = 0; i < 4; ++i)
      #pragma unroll
      for (int r = 0; r < 4; ++r){
        int row = r0 + i*16 + lk*4 + r;
        outv[(size_t)row * DOUT + col] = accV[i][j][r] + bV;
        outc[(size_t)row * DOUT + col] = accC[i][j][r] + bC;
      }
  }
}

extern "C" void kernel_launch(void* const* d_in, const int* in_sizes, int n_in,
                              void* d_out, int out_size, void* d_ws, size_t ws_size,
                              hipStream_t stream)
{
  const float* x    = (const float*)d_in[0];
  const float* gw   = (const float*)d_in[1];
  const float* gb   = (const float*)d_in[2];
  const float* w1   = (const float*)d_in[3];
  const float* b1   = (const float*)d_in[4];
  const float* w2   = (const float*)d_in[5];
  const float* b2   = (const float*)d_in[6];
  const float* clsw = (const float*)d_in[7];
  const float* clsb = (const float*)d_in[8];
  const float* vecw = (const float*)d_in[9];
  const float* vecb = (const float*)d_in[10];

  char* base = (char*)d_out;
  float* combined = (float*)base;                               // [0,32Mi) f32
  float* vec_out  = (float*)(base + (size_t)NTOK*DOUT*4);       // [32,64Mi)
  u16*   h        = (u16*)(base + ((size_t)32<<20));            // [32,48Mi)
  char*  mb       = base + ((size_t)48<<20) + (128<<10);
  int*   tok_slot = (int*)  mb;
  float* w_slot   = (float*)(mb + 131072);
  int*   tke      = (int*)  (mb + 262144);
  float* tkw      = (float*)(mb + 393216);
  int*   counts   = (int*)  (mb + 524288);
  int*   offsets  = (int*)  (mb + 524544);
  int*   cursors  = (int*)  (mb + 524800);
  u16*   w1tb     = (u16*)(base + ((size_t)49<<20));
  u16*   w2tb     = (u16*)(base + ((size_t)52<<20));

  k_zero<<<dim3(1), dim3(64), 0, stream>>>(counts);
  k_gate<<<dim3(NTOK/4), dim3(256), 0, stream>>>(x, gw, gb, tke, tkw, counts);
  k_scan<<<dim3(1), dim3(64), 0, stream>>>(counts, offsets, cursors);
  k_scatter<<<dim3(NTOK/256), dim3(256), 0, stream>>>(tke, tkw, offsets, cursors,
                                                      tok_slot, w_slot);
  k_wt<<<dim3(HDIM/32, DIN/32, NEXP), dim3(256), 0, stream>>>(w1, w1tb, DIN, HDIM);
  k_wt<<<dim3(DOUT/32, HDIM/32, NEXP), dim3(256), 0, stream>>>(w2, w2tb, HDIM, DOUT);
  k_h<<<dim3(256, 2, NEXP), dim3(256), 0, stream>>>(x, w1tb, b1, offsets, tok_slot, h);
  k_y<0><<<dim3(128, 4, NEXP), dim3(256), 0, stream>>>(h, w2tb, b2, offsets, tok_slot, w_slot, combined);
  k_y<1><<<dim3(128, 4, NEXP), dim3(256), 0, stream>>>(h, w2tb, b2, offsets, tok_slot, w_slot, combined);
  // merged finals: vec to [32,64Mi), cls in place over combined
  k_fin<<<dim3(NTOK/64), dim3(512), 0, stream>>>(combined, clsw, vecw, clsb, vecb,
                                                 combined, vec_out);
}

// Round 10
// 262.073 us; speedup vs baseline: 4.1746x; 1.0784x over previous
//
#include <hip/hip_runtime.h>

#define NTOK 16384
#define DIN  512
#define DOUT 512
#define HDIM 256
#define NEXP 10
#define NSLOT (2*NTOK)
#define NSEG  (2*NEXP)
#define BM 128
#define BN 128
#define BK 64

typedef unsigned short u16;
typedef unsigned int   u32;
typedef short s16x8 __attribute__((ext_vector_type(8)));
typedef float f32x4 __attribute__((ext_vector_type(4)));

__device__ __forceinline__ u16 f2b(float f){
  union { float f; u32 u; } c; c.f = f;
  u32 r = c.u + 0x7FFFu + ((c.u >> 16) & 1u);
  return (u16)(r >> 16);
}
__device__ __forceinline__ float b2f(u16 v){
  union { u32 u; float f; } c; c.u = ((u32)v) << 16; return c.f;
}
__device__ __forceinline__ u32 pk2(float lo, float hi){
  return (u32)f2b(lo) | ((u32)f2b(hi) << 16);
}
__device__ __forceinline__ s16x8 cvt8(const float* p){
  f32x4 a = *(const f32x4*)p;
  f32x4 b = *(const f32x4*)(p + 4);
  s16x8 r;
  r[0]=(short)f2b(a[0]); r[1]=(short)f2b(a[1]); r[2]=(short)f2b(a[2]); r[3]=(short)f2b(a[3]);
  r[4]=(short)f2b(b[0]); r[5]=(short)f2b(b[1]); r[6]=(short)f2b(b[2]); r[7]=(short)f2b(b[3]);
  return r;
}

__global__ __launch_bounds__(64) void k_zero(int* counts){
  if (threadIdx.x < NSEG) counts[threadIdx.x] = 0;
}

// ---------------- gating: one wave per token ----------------
__global__ __launch_bounds__(256) void k_gate(
    const float* __restrict__ x, const float* __restrict__ gw, const float* __restrict__ gb,
    int* __restrict__ tke, float* __restrict__ tkw, int* __restrict__ counts)
{
  __shared__ int cnt[NSEG];
  if (threadIdx.x < NSEG) cnt[threadIdx.x] = 0;
  __syncthreads();
  const int wave = threadIdx.x >> 6, lane = threadIdx.x & 63;
  const int token = blockIdx.x * 4 + wave;
  float acc[NEXP];
  #pragma unroll
  for (int e = 0; e < NEXP; ++e) acc[e] = 0.f;
  const float* xr = x + (size_t)token * DIN;
  #pragma unroll
  for (int i = 0; i < DIN/64; ++i){
    int d = lane + 64*i;
    float xv = xr[d];
    const float* g = gw + (size_t)d * NEXP;
    #pragma unroll
    for (int e = 0; e < NEXP; ++e) acc[e] += xv * g[e];
  }
  #pragma unroll
  for (int e = 0; e < NEXP; ++e){
    #pragma unroll
    for (int off = 32; off > 0; off >>= 1) acc[e] += __shfl_xor(acc[e], off, 64);
  }
  if (lane == 0){
    float l[NEXP];
    #pragma unroll
    for (int e = 0; e < NEXP; ++e) l[e] = acc[e] + gb[e];
    int bi = 0; float bv = l[0];
    #pragma unroll
    for (int e = 1; e < NEXP; ++e) if (l[e] > bv){ bv = l[e]; bi = e; }
    int si = -1; float sv = -1e30f;
    #pragma unroll
    for (int e = 0; e < NEXP; ++e) if (e != bi && l[e] > sv){ sv = l[e]; si = e; }
    float w0 = 1.f / (1.f + expf(sv - bv));
    tke[2*token]   = bi;  tke[2*token+1] = si;
    tkw[2*token]   = w0;  tkw[2*token+1] = 1.f - w0;
    atomicAdd(&cnt[2*bi], 1);  atomicAdd(&cnt[2*si+1], 1);
  }
  __syncthreads();
  if (threadIdx.x < NSEG && cnt[threadIdx.x] > 0)
    atomicAdd(&counts[threadIdx.x], cnt[threadIdx.x]);
}

__global__ __launch_bounds__(64) void k_scan(
    const int* __restrict__ counts, int* __restrict__ offsets, int* __restrict__ cursors)
{
  if (threadIdx.x == 0){
    int s = 0;
    for (int i = 0; i < NSEG; ++i){ offsets[i] = s; s += counts[i]; }
    offsets[NSEG] = s;
  }
  if (threadIdx.x < NSEG) cursors[threadIdx.x] = 0;
}

__global__ __launch_bounds__(256) void k_scatter(
    const int* __restrict__ tke, const float* __restrict__ tkw,
    const int* __restrict__ offsets, int* __restrict__ cursors,
    int* __restrict__ tok_slot, float* __restrict__ w_slot)
{
  __shared__ int lcnt[NSEG], lbase[NSEG];
  if (threadIdx.x < NSEG) lcnt[threadIdx.x] = 0;
  __syncthreads();
  int n = blockIdx.x * 256 + threadIdx.x;
  int g0 = 2*tke[2*n], g1 = 2*tke[2*n+1] + 1;
  int p0 = atomicAdd(&lcnt[g0], 1);
  int p1 = atomicAdd(&lcnt[g1], 1);
  __syncthreads();
  if (threadIdx.x < NSEG) lbase[threadIdx.x] = atomicAdd(&cursors[threadIdx.x], lcnt[threadIdx.x]);
  __syncthreads();
  int s0 = offsets[g0] + lbase[g0] + p0;
  int s1 = offsets[g1] + lbase[g1] + p1;
  tok_slot[s0] = n; w_slot[s0] = tkw[2*n];
  tok_slot[s1] = n; w_slot[s1] = tkw[2*n+1];
}

// ---------------- prep: weight transpose+cvt  in[R][C] f32 -> out[C][R] bf16 ----------------
__global__ __launch_bounds__(256) void k_wt(
    const float* __restrict__ in, u16* __restrict__ out, int R, int C)
{
  __shared__ float tile[32][33];
  const float* src = in + (size_t)blockIdx.z * R * C;
  u16* dst = out + (size_t)blockIdx.z * R * C;
  int cb = blockIdx.x * 32, rb = blockIdx.y * 32;
  int tx = threadIdx.x & 31, ty = threadIdx.x >> 5;
  #pragma unroll
  for (int i = 0; i < 4; ++i)
    tile[ty + i*8][tx] = src[(size_t)(rb + ty + i*8) * C + cb + tx];
  __syncthreads();
  #pragma unroll
  for (int i = 0; i < 4; ++i)
    dst[(size_t)(cb + ty + i*8) * R + rb + tx] = f2b(tile[tx][ty + i*8]);
}

// ---------------- k_h: h = relu(x[tok] W1e + b1e), gathered A, LDS epilogue ----------------
__global__ __launch_bounds__(256, 2) void k_h(
    const float* __restrict__ x, const u16* __restrict__ w1tb, const float* __restrict__ b1,
    const int* __restrict__ offsets, const int* __restrict__ tok_slot,
    u16* __restrict__ h)
{
  __shared__ __align__(16) char pool[65536];
  u16* As = (u16*)pool;
  u16* Bs = (u16*)(pool + 32768);
  __shared__ int toks[BM];
  const int e   = blockIdx.z;
  const int off = offsets[2*e];
  const int cnt = offsets[2*e+2] - off;
  const int c0  = blockIdx.x * BM;
  if (c0 >= cnt) return;
  const int n0  = blockIdx.y * BN;
  const int tid = threadIdx.x;

  if (tid < BM){
    int r = c0 + tid;
    toks[tid] = tok_slot[off + (r < cnt ? r : cnt - 1)];
  }
  __syncthreads();

  const u16* Bg = w1tb + ((size_t)e * HDIM + n0) * DIN;

  int crow[4], ckk[4];
  #pragma unroll
  for (int i = 0; i < 4; ++i){
    int c = tid + i*256;
    crow[i] = c >> 3; ckk[i] = (c & 7) * 8;
  }
  int tokr[4];
  #pragma unroll
  for (int i = 0; i < 4; ++i) tokr[i] = toks[crow[i]];

  s16x8 ra[4], rb[4];
  auto loadregs = [&](int ks){
    #pragma unroll
    for (int i = 0; i < 4; ++i){
      ra[i] = cvt8(x + (size_t)tokr[i]*DIN + ks*BK + ckk[i]);
      rb[i] = *(const s16x8*)(Bg + (size_t)crow[i]*DIN + ks*BK + ckk[i]);
    }
  };
  auto writeregs = [&](int buf){
    #pragma unroll
    for (int i = 0; i < 4; ++i){
      u32 byt = (u32)((crow[i]*BK + ckk[i])*2) ^ ((u32)(crow[i]&7)<<4);
      *(s16x8*)((char*)As + buf*16384 + byt) = ra[i];
      *(s16x8*)((char*)Bs + buf*16384 + byt) = rb[i];
    }
  };

  const int wv = tid >> 6, lane = tid & 63;
  const int lr = lane & 15, lk = lane >> 4;
  const int wr = (wv >> 1) * 64, wc = (wv & 1) * 64;

  f32x4 acc[4][4];
  #pragma unroll
  for (int i = 0; i < 4; ++i)
    #pragma unroll
    for (int j = 0; j < 4; ++j) acc[i][j] = (f32x4){0.f,0.f,0.f,0.f};

  loadregs(0); writeregs(0);
  int cur = 0;
  const int NK = DIN / BK;
  for (int ks = 0; ks < NK; ++ks){
    __syncthreads();
    if (ks + 1 < NK) loadregs(ks + 1);
    #pragma unroll
    for (int sub = 0; sub < 2; ++sub){
      s16x8 af[4], bf[4];
      #pragma unroll
      for (int g = 0; g < 4; ++g){
        int arow = wr + g*16 + lr;
        u32 ab = (u32)((arow*BK + sub*32 + lk*8)*2) ^ ((u32)(arow&7)<<4);
        af[g] = *(const s16x8*)((char*)As + cur*16384 + ab);
        int bcol = wc + g*16 + lr;
        u32 bb = (u32)((bcol*BK + sub*32 + lk*8)*2) ^ ((u32)(bcol&7)<<4);
        bf[g] = *(const s16x8*)((char*)Bs + cur*16384 + bb);
      }
      #pragma unroll
      for (int i = 0; i < 4; ++i)
        #pragma unroll
        for (int j = 0; j < 4; ++j)
          acc[i][j] = __builtin_amdgcn_mfma_f32_16x16x32_bf16(af[i], bf[j], acc[i][j], 0, 0, 0);
    }
    if (ks + 1 < NK) writeregs(cur ^ 1);
    cur ^= 1;
  }
  __syncthreads();

  u16* outh = (u16*)pool;            // [128][136]
  #pragma unroll
  for (int j = 0; j < 4; ++j){
    int col = wc + j*16 + lr;
    float bias = b1[e*HDIM + n0 + col];
    #pragma unroll
    for (int i = 0; i < 4; ++i)
      #pragma unroll
      for (int r = 0; r < 4; ++r){
        int row = wr + i*16 + lk*4 + r;
        float v = acc[i][j][r] + bias;
        outh[row*136 + col] = f2b(v > 0.f ? v : 0.f);
      }
  }
  __syncthreads();
  {
    int r = tid >> 1, half = tid & 1;
    if (c0 + r < cnt){
      u16* dst = h + (size_t)(off + c0 + r) * HDIM + n0 + half*64;
      const u16* src = outh + r*136 + half*64;
      #pragma unroll
      for (int q = 0; q < 8; ++q)
        *(s16x8*)(dst + q*8) = *(const s16x8*)(src + q*8);
    }
  }
}

// ---------------- k_y: bf16-strided combined (+)= w_slot * (h W2e + b2e) ----------------
// cmb: strided layout, token t occupies u16[t*1024 .. t*1024+512) (first half of
// its 2048B cls-output row). PASS0 writes, PASS1 does bf16 RMW (unique writer).
template<int PASS>
__global__ __launch_bounds__(256, 2) void k_y(
    const u16* __restrict__ h, const u16* __restrict__ w2tb, const float* __restrict__ b2,
    const int* __restrict__ offsets, const int* __restrict__ tok_slot,
    const float* __restrict__ w_slot, u16* __restrict__ cmb)
{
  __shared__ __align__(16) char pool[67584];
  u16* As = (u16*)pool;
  u16* Bs = (u16*)(pool + 32768);
  __shared__ int   toks[BM];
  __shared__ float wts[BM];
  const int e    = blockIdx.z;
  const int segb = offsets[2*e + PASS];
  const int segc = offsets[2*e + PASS + 1] - segb;
  const int c0   = blockIdx.x * BM;
  if (c0 >= segc) return;
  const int n0   = blockIdx.y * BN;
  const int tid  = threadIdx.x;

  if (tid < BM){
    int r = c0 + tid;
    int s = segb + (r < segc ? r : segc - 1);
    toks[tid] = tok_slot[s];
    wts[tid]  = w_slot[s];
  }

  const u16* Ag = h + (size_t)(segb + c0) * HDIM;
  const u16* Bg = w2tb + ((size_t)e * DOUT + n0) * HDIM;

  int crow[4], ckk[4];
  #pragma unroll
  for (int i = 0; i < 4; ++i){
    int c = tid + i*256;
    crow[i] = c >> 3; ckk[i] = (c & 7) * 8;
  }
  s16x8 ra[4], rb[4];
  auto loadregs = [&](int ks){
    #pragma unroll
    for (int i = 0; i < 4; ++i){
      ra[i] = *(const s16x8*)(Ag + (size_t)crow[i]*HDIM + ks*BK + ckk[i]);
      rb[i] = *(const s16x8*)(Bg + (size_t)crow[i]*HDIM + ks*BK + ckk[i]);
    }
  };
  auto writeregs = [&](int buf){
    #pragma unroll
    for (int i = 0; i < 4; ++i){
      u32 byt = (u32)((crow[i]*BK + ckk[i])*2) ^ ((u32)(crow[i]&7)<<4);
      *(s16x8*)((char*)As + buf*16384 + byt) = ra[i];
      *(s16x8*)((char*)Bs + buf*16384 + byt) = rb[i];
    }
  };

  const int wv = tid >> 6, lane = tid & 63;
  const int lr = lane & 15, lk = lane >> 4;
  const int wr = (wv >> 1) * 64, wc = (wv & 1) * 64;

  f32x4 acc[4][4];
  #pragma unroll
  for (int i = 0; i < 4; ++i)
    #pragma unroll
    for (int j = 0; j < 4; ++j) acc[i][j] = (f32x4){0.f,0.f,0.f,0.f};

  loadregs(0); writeregs(0);
  int cur = 0;
  const int NK = HDIM / BK;
  for (int ks = 0; ks < NK; ++ks){
    __syncthreads();
    if (ks + 1 < NK) loadregs(ks + 1);
    #pragma unroll
    for (int sub = 0; sub < 2; ++sub){
      s16x8 af[4], bf[4];
      #pragma unroll
      for (int g = 0; g < 4; ++g){
        int arow = wr + g*16 + lr;
        u32 ab = (u32)((arow*BK + sub*32 + lk*8)*2) ^ ((u32)(arow&7)<<4);
        af[g] = *(const s16x8*)((char*)As + cur*16384 + ab);
        int bcol = wc + g*16 + lr;
        u32 bb = (u32)((bcol*BK + sub*32 + lk*8)*2) ^ ((u32)(bcol&7)<<4);
        bf[g] = *(const s16x8*)((char*)Bs + cur*16384 + bb);
      }
      #pragma unroll
      for (int i = 0; i < 4; ++i)
        #pragma unroll
        for (int j = 0; j < 4; ++j)
          acc[i][j] = __builtin_amdgcn_mfma_f32_16x16x32_bf16(af[i], bf[j], acc[i][j], 0, 0, 0);
    }
    if (ks + 1 < NK) writeregs(cur ^ 1);
    cur ^= 1;
  }
  __syncthreads();

  float* outf = (float*)pool;        // [128][132]
  #pragma unroll
  for (int j = 0; j < 4; ++j){
    int col = wc + j*16 + lr;
    float bias = b2[e*DOUT + n0 + col];
    #pragma unroll
    for (int i = 0; i < 4; ++i)
      #pragma unroll
      for (int r = 0; r < 4; ++r){
        int row = wr + i*16 + lk*4 + r;
        outf[row*132 + col] = wts[row] * (acc[i][j][r] + bias);
      }
  }
  __syncthreads();
  {
    int r = tid >> 1, half = tid & 1;
    if (c0 + r < segc){
      u16* dst = cmb + (size_t)toks[r] * 1024 + n0 + half*64;
      const float* src = outf + r*132 + half*64;
      #pragma unroll
      for (int q = 0; q < 8; ++q){
        s16x8 o;
        if (PASS == 0){
          #pragma unroll
          for (int m = 0; m < 8; ++m) o[m] = (short)f2b(src[q*8 + m]);
        } else {
          s16x8 old = *(const s16x8*)(dst + q*8);
          #pragma unroll
          for (int m = 0; m < 8; ++m)
            o[m] = (short)f2b(b2f((u16)old[m]) + src[q*8 + m]);
        }
        *(s16x8*)(dst + q*8) = o;
      }
    }
  }
}

// ---------------- k_vec: out[32,64M) = strided-A @ vecw + bias (disjoint, free tiling) ----
// 256 rows x 128 cols per block; B dbuf 20KB; A direct-from-global bf16 strided.
__global__ __launch_bounds__(512, 4) void k_vec(
    const u16* __restrict__ cmb, const float* __restrict__ W,
    const float* __restrict__ bias, float* __restrict__ out)
{
  __shared__ __align__(16) char Bs[2][10240];   // 128 cols x 80B
  const int tid = threadIdx.x;
  const int r0  = blockIdx.x * 256;
  const int c0  = blockIdx.y * 128;

  const int bc4 = tid >> 4;          // 0..31
  const int bkp = tid & 15;          // 0..15
  u32 bpk[4];
  auto loadB = [&](int ks){
    const float* p0 = W + (size_t)(ks*32 + 2*bkp) * DOUT + c0 + bc4*4;
    f32x4 v0 = *(const f32x4*)p0;
    f32x4 v1 = *(const f32x4*)(p0 + DOUT);
    #pragma unroll
    for (int m = 0; m < 4; ++m) bpk[m] = pk2(v0[m], v1[m]);
  };
  auto writeB = [&](int buf){
    #pragma unroll
    for (int m = 0; m < 4; ++m)
      *(u32*)(Bs[buf] + (bc4*4 + m)*80 + bkp*4) = bpk[m];
  };

  const int wv = tid >> 6, lane = tid & 63;
  const int lr = lane & 15, lk = lane >> 4;
  const int rg = wv >> 1, cg = wv & 1;
  const u16* Arow = cmb + (size_t)(r0 + rg*64) * 1024;

  f32x4 acc[4][4];
  #pragma unroll
  for (int i = 0; i < 4; ++i)
    #pragma unroll
    for (int j = 0; j < 4; ++j) acc[i][j] = (f32x4){0.f,0.f,0.f,0.f};

  s16x8 af[4], afn[4];
  auto loadA = [&](s16x8* a, int ks){
    #pragma unroll
    for (int g = 0; g < 4; ++g)
      a[g] = *(const s16x8*)(Arow + (size_t)(g*16 + lr)*1024 + ks*32 + lk*8);
  };

  loadB(0); writeB(0); loadA(af, 0);
  int cur = 0;
  for (int ks = 0; ks < 16; ++ks){
    __syncthreads();
    if (ks + 1 < 16){ loadB(ks + 1); loadA(afn, ks + 1); }
    s16x8 bf[4];
    #pragma unroll
    for (int j = 0; j < 4; ++j)
      bf[j] = *(const s16x8*)(Bs[cur] + (cg*64 + j*16 + lr)*80 + lk*16);
    #pragma unroll
    for (int i = 0; i < 4; ++i)
      #pragma unroll
      for (int j = 0; j < 4; ++j)
        acc[i][j] = __builtin_amdgcn_mfma_f32_16x16x32_bf16(af[i], bf[j], acc[i][j], 0, 0, 0);
    if (ks + 1 < 16) writeB(cur ^ 1);
    #pragma unroll
    for (int g = 0; g < 4; ++g) af[g] = afn[g];
    cur ^= 1;
  }

  #pragma unroll
  for (int j = 0; j < 4; ++j){
    int col = c0 + cg*64 + j*16 + lr;
    float bv = bias[col];
    #pragma unroll
    for (int i = 0; i < 4; ++i)
      #pragma unroll
      for (int r = 0; r < 4; ++r){
        int row = r0 + rg*64 + i*16 + lk*4 + r;
        out[(size_t)row * DOUT + col] = acc[i][j][r] + bv;
      }
  }
}

// ---------------- k_cls: in-place over [0,32M): self-contained 64 rows x 512 cols ----------
__global__ __launch_bounds__(512, 4) void k_cls(
    const float* __restrict__ W, const float* __restrict__ bias,
    u16* __restrict__ cmbio)
{
  __shared__ __align__(16) char Bs[40960];   // 512 cols x 80B
  const int tid = threadIdx.x;
  const int r0  = blockIdx.x * 64;

  int bc4[4], bkp[4];
  #pragma unroll
  for (int u = 0; u < 4; ++u){
    int idx = tid + u*512;
    bc4[u] = idx >> 4;               // 0..127
    bkp[u] = idx & 15;               // 0..15
  }
  u32 bpk[4][4];
  auto loadB = [&](int ks){
    #pragma unroll
    for (int u = 0; u < 4; ++u){
      const float* p0 = W + (size_t)(ks*32 + 2*bkp[u]) * DOUT + bc4[u]*4;
      f32x4 v0 = *(const f32x4*)p0;
      f32x4 v1 = *(const f32x4*)(p0 + DOUT);
      #pragma unroll
      for (int m = 0; m < 4; ++m) bpk[u][m] = pk2(v0[m], v1[m]);
    }
  };
  auto writeB = [&](){
    #pragma unroll
    for (int u = 0; u < 4; ++u)
      #pragma unroll
      for (int m = 0; m < 4; ++m)
        *(u32*)(Bs + (bc4[u]*4 + m)*80 + bkp[u]*4) = bpk[u][m];
  };

  const int wv = tid >> 6, lane = tid & 63;
  const int lr = lane & 15, lk = lane >> 4;
  const int wc = wv * 64;
  const u16* Arow = cmbio + (size_t)r0 * 1024;

  f32x4 acc[4][4];
  #pragma unroll
  for (int i = 0; i < 4; ++i)
    #pragma unroll
    for (int j = 0; j < 4; ++j) acc[i][j] = (f32x4){0.f,0.f,0.f,0.f};

  loadB(0);
  for (int ks = 0; ks < 16; ++ks){
    __syncthreads();                 // prior Bs reads done
    writeB();
    __syncthreads();                 // Bs ready
    if (ks + 1 < 16) loadB(ks + 1);
    s16x8 af[4], bf[4];
    #pragma unroll
    for (int g = 0; g < 4; ++g){
      af[g] = *(const s16x8*)(Arow + (size_t)(g*16 + lr)*1024 + ks*32 + lk*8);
      bf[g] = *(const s16x8*)(Bs + (wc + g*16 + lr)*80 + lk*16);
    }
    #pragma unroll
    for (int i = 0; i < 4; ++i)
      #pragma unroll
      for (int j = 0; j < 4; ++j)
        acc[i][j] = __builtin_amdgcn_mfma_f32_16x16x32_bf16(af[i], bf[j], acc[i][j], 0, 0, 0);
  }
  __syncthreads();   // drain ALL waves' A reads before in-place overwrite

  float* out = (float*)cmbio;        // f32 view, row stride DOUT
  #pragma unroll
  for (int j = 0; j < 4; ++j){
    int col = wc + j*16 + lr;
    float bv = bias[col];
    #pragma unroll
    for (int i = 0; i < 4; ++i)
      #pragma unroll
      for (int r = 0; r < 4; ++r){
        int row = r0 + i*16 + lk*4 + r;
        out[(size_t)row * DOUT + col] = acc[i][j][r] + bv;
      }
  }
}

extern "C" void kernel_launch(void* const* d_in, const int* in_sizes, int n_in,
                              void* d_out, int out_size, void* d_ws, size_t ws_size,
                              hipStream_t stream)
{
  const float* x    = (const float*)d_in[0];
  const float* gw   = (const float*)d_in[1];
  const float* gb   = (const float*)d_in[2];
  const float* w1   = (const float*)d_in[3];
  const float* b1   = (const float*)d_in[4];
  const float* w2   = (const float*)d_in[5];
  const float* b2   = (const float*)d_in[6];
  const float* clsw = (const float*)d_in[7];
  const float* clsb = (const float*)d_in[8];
  const float* vecw = (const float*)d_in[9];
  const float* vecb = (const float*)d_in[10];

  char* base = (char*)d_out;
  u16*   cmb      = (u16*)base;                                 // strided bf16 combined in [0,32Mi)
  float* vec_out  = (float*)(base + (size_t)NTOK*DOUT*4);       // [32,64Mi)
  u16*   h        = (u16*)(base + ((size_t)32<<20));            // [32,48Mi), dead before k_vec
  char*  mb       = base + ((size_t)48<<20) + (128<<10);
  int*   tok_slot = (int*)  mb;
  float* w_slot   = (float*)(mb + 131072);
  int*   tke      = (int*)  (mb + 262144);
  float* tkw      = (float*)(mb + 393216);
  int*   counts   = (int*)  (mb + 524288);
  int*   offsets  = (int*)  (mb + 524544);
  int*   cursors  = (int*)  (mb + 524800);
  u16*   w1tb     = (u16*)(base + ((size_t)49<<20));
  u16*   w2tb     = (u16*)(base + ((size_t)52<<20));

  k_zero<<<dim3(1), dim3(64), 0, stream>>>(counts);
  k_gate<<<dim3(NTOK/4), dim3(256), 0, stream>>>(x, gw, gb, tke, tkw, counts);
  k_scan<<<dim3(1), dim3(64), 0, stream>>>(counts, offsets, cursors);
  k_scatter<<<dim3(NTOK/256), dim3(256), 0, stream>>>(tke, tkw, offsets, cursors,
                                                      tok_slot, w_slot);
  k_wt<<<dim3(HDIM/32, DIN/32, NEXP), dim3(256), 0, stream>>>(w1, w1tb, DIN, HDIM);
  k_wt<<<dim3(DOUT/32, HDIM/32, NEXP), dim3(256), 0, stream>>>(w2, w2tb, HDIM, DOUT);
  k_h<<<dim3(256, 2, NEXP), dim3(256), 0, stream>>>(x, w1tb, b1, offsets, tok_slot, h);
  k_y<0><<<dim3(128, 4, NEXP), dim3(256), 0, stream>>>(h, w2tb, b2, offsets, tok_slot, w_slot, cmb);
  k_y<1><<<dim3(128, 4, NEXP), dim3(256), 0, stream>>>(h, w2tb, b2, offsets, tok_slot, w_slot, cmb);
  // vec first: reads strided cmb in [0,32Mi), writes [32,64Mi) — disjoint.
  k_vec<<<dim3(NTOK/256, DOUT/128), dim3(512), 0, stream>>>(cmb, vecw, vecb, vec_out);
  // cls last: self-contained rows, in place over [0,32Mi).
  k_cls<<<dim3(NTOK/64), dim3(512), 0, stream>>>(clsw, clsb, cmb);
}

// Round 11
// 252.231 us; speedup vs baseline: 4.3375x; 1.0390x over previous
//
#include <hip/hip_runtime.h>

#define NTOK 16384
#define DIN  512
#define DOUT 512
#define HDIM 256
#define NEXP 10
#define NSLOT (2*NTOK)
#define NSEG  (2*NEXP)
#define BM 128
#define BN 128
#define BK 64

typedef unsigned short u16;
typedef unsigned int   u32;
typedef short s16x8 __attribute__((ext_vector_type(8)));
typedef float f32x4 __attribute__((ext_vector_type(4)));

__device__ __forceinline__ u16 f2b(float f){
  union { float f; u32 u; } c; c.f = f;
  u32 r = c.u + 0x7FFFu + ((c.u >> 16) & 1u);
  return (u16)(r >> 16);
}
__device__ __forceinline__ float b2f(u16 v){
  union { u32 u; float f; } c; c.u = ((u32)v) << 16; return c.f;
}
__device__ __forceinline__ u32 pk2(float lo, float hi){
  return (u32)f2b(lo) | ((u32)f2b(hi) << 16);
}
__device__ __forceinline__ s16x8 cvt8(const float* p){
  f32x4 a = *(const f32x4*)p;
  f32x4 b = *(const f32x4*)(p + 4);
  s16x8 r;
  r[0]=(short)f2b(a[0]); r[1]=(short)f2b(a[1]); r[2]=(short)f2b(a[2]); r[3]=(short)f2b(a[3]);
  r[4]=(short)f2b(b[0]); r[5]=(short)f2b(b[1]); r[6]=(short)f2b(b[2]); r[7]=(short)f2b(b[3]);
  return r;
}

__global__ __launch_bounds__(64) void k_zero(int* counts){
  if (threadIdx.x < NSEG) counts[threadIdx.x] = 0;
}

// ---------------- gating: one wave per token ----------------
__global__ __launch_bounds__(256) void k_gate(
    const float* __restrict__ x, const float* __restrict__ gw, const float* __restrict__ gb,
    int* __restrict__ tke, float* __restrict__ tkw, int* __restrict__ counts)
{
  __shared__ int cnt[NSEG];
  if (threadIdx.x < NSEG) cnt[threadIdx.x] = 0;
  __syncthreads();
  const int wave = threadIdx.x >> 6, lane = threadIdx.x & 63;
  const int token = blockIdx.x * 4 + wave;
  float acc[NEXP];
  #pragma unroll
  for (int e = 0; e < NEXP; ++e) acc[e] = 0.f;
  const float* xr = x + (size_t)token * DIN;
  #pragma unroll
  for (int i = 0; i < DIN/64; ++i){
    int d = lane + 64*i;
    float xv = xr[d];
    const float* g = gw + (size_t)d * NEXP;
    #pragma unroll
    for (int e = 0; e < NEXP; ++e) acc[e] += xv * g[e];
  }
  #pragma unroll
  for (int e = 0; e < NEXP; ++e){
    #pragma unroll
    for (int off = 32; off > 0; off >>= 1) acc[e] += __shfl_xor(acc[e], off, 64);
  }
  if (lane == 0){
    float l[NEXP];
    #pragma unroll
    for (int e = 0; e < NEXP; ++e) l[e] = acc[e] + gb[e];
    int bi = 0; float bv = l[0];
    #pragma unroll
    for (int e = 1; e < NEXP; ++e) if (l[e] > bv){ bv = l[e]; bi = e; }
    int si = -1; float sv = -1e30f;
    #pragma unroll
    for (int e = 0; e < NEXP; ++e) if (e != bi && l[e] > sv){ sv = l[e]; si = e; }
    float w0 = 1.f / (1.f + expf(sv - bv));
    tke[2*token]   = bi;  tke[2*token+1] = si;
    tkw[2*token]   = w0;  tkw[2*token+1] = 1.f - w0;
    atomicAdd(&cnt[2*bi], 1);  atomicAdd(&cnt[2*si+1], 1);
  }
  __syncthreads();
  if (threadIdx.x < NSEG && cnt[threadIdx.x] > 0)
    atomicAdd(&counts[threadIdx.x], cnt[threadIdx.x]);
}

__global__ __launch_bounds__(64) void k_scan(
    const int* __restrict__ counts, int* __restrict__ offsets, int* __restrict__ cursors)
{
  if (threadIdx.x == 0){
    int s = 0;
    for (int i = 0; i < NSEG; ++i){ offsets[i] = s; s += counts[i]; }
    offsets[NSEG] = s;
  }
  if (threadIdx.x < NSEG) cursors[threadIdx.x] = 0;
}

__global__ __launch_bounds__(256) void k_scatter(
    const int* __restrict__ tke, const float* __restrict__ tkw,
    const int* __restrict__ offsets, int* __restrict__ cursors,
    int* __restrict__ tok_slot, float* __restrict__ w_slot)
{
  __shared__ int lcnt[NSEG], lbase[NSEG];
  if (threadIdx.x < NSEG) lcnt[threadIdx.x] = 0;
  __syncthreads();
  int n = blockIdx.x * 256 + threadIdx.x;
  int g0 = 2*tke[2*n], g1 = 2*tke[2*n+1] + 1;
  int p0 = atomicAdd(&lcnt[g0], 1);
  int p1 = atomicAdd(&lcnt[g1], 1);
  __syncthreads();
  if (threadIdx.x < NSEG) lbase[threadIdx.x] = atomicAdd(&cursors[threadIdx.x], lcnt[threadIdx.x]);
  __syncthreads();
  int s0 = offsets[g0] + lbase[g0] + p0;
  int s1 = offsets[g1] + lbase[g1] + p1;
  tok_slot[s0] = n; w_slot[s0] = tkw[2*n];
  tok_slot[s1] = n; w_slot[s1] = tkw[2*n+1];
}

// ---------------- prep: weight transpose+cvt  in[R][C] f32 -> out[C][R] bf16 ----------------
__global__ __launch_bounds__(256) void k_wt(
    const float* __restrict__ in, u16* __restrict__ out, int R, int C)
{
  __shared__ float tile[32][33];
  const float* src = in + (size_t)blockIdx.z * R * C;
  u16* dst = out + (size_t)blockIdx.z * R * C;
  int cb = blockIdx.x * 32, rb = blockIdx.y * 32;
  int tx = threadIdx.x & 31, ty = threadIdx.x >> 5;
  #pragma unroll
  for (int i = 0; i < 4; ++i)
    tile[ty + i*8][tx] = src[(size_t)(rb + ty + i*8) * C + cb + tx];
  __syncthreads();
  #pragma unroll
  for (int i = 0; i < 4; ++i)
    dst[(size_t)(cb + ty + i*8) * R + rb + tx] = f2b(tile[tx][ty + i*8]);
}

// ---------------- k_h: h = relu(x[tok] W1e + b1e), gathered A, LDS epilogue ----------------
__global__ __launch_bounds__(256, 2) void k_h(
    const float* __restrict__ x, const u16* __restrict__ w1tb, const float* __restrict__ b1,
    const int* __restrict__ offsets, const int* __restrict__ tok_slot,
    u16* __restrict__ h)
{
  __shared__ __align__(16) char pool[65536];
  u16* As = (u16*)pool;
  u16* Bs = (u16*)(pool + 32768);
  __shared__ int toks[BM];
  const int e   = blockIdx.z;
  const int off = offsets[2*e];
  const int cnt = offsets[2*e+2] - off;
  const int c0  = blockIdx.x * BM;
  if (c0 >= cnt) return;
  const int n0  = blockIdx.y * BN;
  const int tid = threadIdx.x;

  if (tid < BM){
    int r = c0 + tid;
    toks[tid] = tok_slot[off + (r < cnt ? r : cnt - 1)];
  }
  __syncthreads();

  const u16* Bg = w1tb + ((size_t)e * HDIM + n0) * DIN;

  int crow[4], ckk[4];
  #pragma unroll
  for (int i = 0; i < 4; ++i){
    int c = tid + i*256;
    crow[i] = c >> 3; ckk[i] = (c & 7) * 8;
  }
  int tokr[4];
  #pragma unroll
  for (int i = 0; i < 4; ++i) tokr[i] = toks[crow[i]];

  s16x8 ra[4], rb[4];
  auto loadregs = [&](int ks){
    #pragma unroll
    for (int i = 0; i < 4; ++i){
      ra[i] = cvt8(x + (size_t)tokr[i]*DIN + ks*BK + ckk[i]);
      rb[i] = *(const s16x8*)(Bg + (size_t)crow[i]*DIN + ks*BK + ckk[i]);
    }
  };
  auto writeregs = [&](int buf){
    #pragma unroll
    for (int i = 0; i < 4; ++i){
      u32 byt = (u32)((crow[i]*BK + ckk[i])*2) ^ ((u32)(crow[i]&7)<<4);
      *(s16x8*)((char*)As + buf*16384 + byt) = ra[i];
      *(s16x8*)((char*)Bs + buf*16384 + byt) = rb[i];
    }
  };

  const int wv = tid >> 6, lane = tid & 63;
  const int lr = lane & 15, lk = lane >> 4;
  const int wr = (wv >> 1) * 64, wc = (wv & 1) * 64;

  f32x4 acc[4][4];
  #pragma unroll
  for (int i = 0; i < 4; ++i)
    #pragma unroll
    for (int j = 0; j < 4; ++j) acc[i][j] = (f32x4){0.f,0.f,0.f,0.f};

  loadregs(0); writeregs(0);
  int cur = 0;
  const int NK = DIN / BK;
  for (int ks = 0; ks < NK; ++ks){
    __syncthreads();
    if (ks + 1 < NK) loadregs(ks + 1);
    #pragma unroll
    for (int sub = 0; sub < 2; ++sub){
      s16x8 af[4], bf[4];
      #pragma unroll
      for (int g = 0; g < 4; ++g){
        int arow = wr + g*16 + lr;
        u32 ab = (u32)((arow*BK + sub*32 + lk*8)*2) ^ ((u32)(arow&7)<<4);
        af[g] = *(const s16x8*)((char*)As + cur*16384 + ab);
        int bcol = wc + g*16 + lr;
        u32 bb = (u32)((bcol*BK + sub*32 + lk*8)*2) ^ ((u32)(bcol&7)<<4);
        bf[g] = *(const s16x8*)((char*)Bs + cur*16384 + bb);
      }
      #pragma unroll
      for (int i = 0; i < 4; ++i)
        #pragma unroll
        for (int j = 0; j < 4; ++j)
          acc[i][j] = __builtin_amdgcn_mfma_f32_16x16x32_bf16(af[i], bf[j], acc[i][j], 0, 0, 0);
    }
    if (ks + 1 < NK) writeregs(cur ^ 1);
    cur ^= 1;
  }
  __syncthreads();

  u16* outh = (u16*)pool;            // [128][136]
  #pragma unroll
  for (int j = 0; j < 4; ++j){
    int col = wc + j*16 + lr;
    float bias = b1[e*HDIM + n0 + col];
    #pragma unroll
    for (int i = 0; i < 4; ++i)
      #pragma unroll
      for (int r = 0; r < 4; ++r){
        int row = wr + i*16 + lk*4 + r;
        float v = acc[i][j][r] + bias;
        outh[row*136 + col] = f2b(v > 0.f ? v : 0.f);
      }
  }
  __syncthreads();
  {
    int r = tid >> 1, half = tid & 1;
    if (c0 + r < cnt){
      u16* dst = h + (size_t)(off + c0 + r) * HDIM + n0 + half*64;
      const u16* src = outh + r*136 + half*64;
      #pragma unroll
      for (int q = 0; q < 8; ++q)
        *(s16x8*)(dst + q*8) = *(const s16x8*)(src + q*8);
    }
  }
}

// ---------------- k_y: bf16-strided combined (+)= w_slot * (h W2e + b2e) ----------------
// cmb strided: token t occupies u16[t*1024 .. t*1024+512) (first half of its
// vec-output row at base+32Mi). PASS0 writes, PASS1 does bf16 RMW.
template<int PASS>
__global__ __launch_bounds__(256, 2) void k_y(
    const u16* __restrict__ h, const u16* __restrict__ w2tb, const float* __restrict__ b2,
    const int* __restrict__ offsets, const int* __restrict__ tok_slot,
    const float* __restrict__ w_slot, u16* __restrict__ cmb)
{
  __shared__ __align__(16) char pool[67584];
  u16* As = (u16*)pool;
  u16* Bs = (u16*)(pool + 32768);
  __shared__ int   toks[BM];
  __shared__ float wts[BM];
  const int e    = blockIdx.z;
  const int segb = offsets[2*e + PASS];
  const int segc = offsets[2*e + PASS + 1] - segb;
  const int c0   = blockIdx.x * BM;
  if (c0 >= segc) return;
  const int n0   = blockIdx.y * BN;
  const int tid  = threadIdx.x;

  if (tid < BM){
    int r = c0 + tid;
    int s = segb + (r < segc ? r : segc - 1);
    toks[tid] = tok_slot[s];
    wts[tid]  = w_slot[s];
  }

  const u16* Ag = h + (size_t)(segb + c0) * HDIM;
  const u16* Bg = w2tb + ((size_t)e * DOUT + n0) * HDIM;

  int crow[4], ckk[4];
  #pragma unroll
  for (int i = 0; i < 4; ++i){
    int c = tid + i*256;
    crow[i] = c >> 3; ckk[i] = (c & 7) * 8;
  }
  s16x8 ra[4], rb[4];
  auto loadregs = [&](int ks){
    #pragma unroll
    for (int i = 0; i < 4; ++i){
      ra[i] = *(const s16x8*)(Ag + (size_t)crow[i]*HDIM + ks*BK + ckk[i]);
      rb[i] = *(const s16x8*)(Bg + (size_t)crow[i]*HDIM + ks*BK + ckk[i]);
    }
  };
  auto writeregs = [&](int buf){
    #pragma unroll
    for (int i = 0; i < 4; ++i){
      u32 byt = (u32)((crow[i]*BK + ckk[i])*2) ^ ((u32)(crow[i]&7)<<4);
      *(s16x8*)((char*)As + buf*16384 + byt) = ra[i];
      *(s16x8*)((char*)Bs + buf*16384 + byt) = rb[i];
    }
  };

  const int wv = tid >> 6, lane = tid & 63;
  const int lr = lane & 15, lk = lane >> 4;
  const int wr = (wv >> 1) * 64, wc = (wv & 1) * 64;

  f32x4 acc[4][4];
  #pragma unroll
  for (int i = 0; i < 4; ++i)
    #pragma unroll
    for (int j = 0; j < 4; ++j) acc[i][j] = (f32x4){0.f,0.f,0.f,0.f};

  loadregs(0); writeregs(0);
  int cur = 0;
  const int NK = HDIM / BK;
  for (int ks = 0; ks < NK; ++ks){
    __syncthreads();
    if (ks + 1 < NK) loadregs(ks + 1);
    #pragma unroll
    for (int sub = 0; sub < 2; ++sub){
      s16x8 af[4], bf[4];
      #pragma unroll
      for (int g = 0; g < 4; ++g){
        int arow = wr + g*16 + lr;
        u32 ab = (u32)((arow*BK + sub*32 + lk*8)*2) ^ ((u32)(arow&7)<<4);
        af[g] = *(const s16x8*)((char*)As + cur*16384 + ab);
        int bcol = wc + g*16 + lr;
        u32 bb = (u32)((bcol*BK + sub*32 + lk*8)*2) ^ ((u32)(bcol&7)<<4);
        bf[g] = *(const s16x8*)((char*)Bs + cur*16384 + bb);
      }
      #pragma unroll
      for (int i = 0; i < 4; ++i)
        #pragma unroll
        for (int j = 0; j < 4; ++j)
          acc[i][j] = __builtin_amdgcn_mfma_f32_16x16x32_bf16(af[i], bf[j], acc[i][j], 0, 0, 0);
    }
    if (ks + 1 < NK) writeregs(cur ^ 1);
    cur ^= 1;
  }
  __syncthreads();

  float* outf = (float*)pool;        // [128][132]
  #pragma unroll
  for (int j = 0; j < 4; ++j){
    int col = wc + j*16 + lr;
    float bias = b2[e*DOUT + n0 + col];
    #pragma unroll
    for (int i = 0; i < 4; ++i)
      #pragma unroll
      for (int r = 0; r < 4; ++r){
        int row = wr + i*16 + lk*4 + r;
        outf[row*132 + col] = wts[row] * (acc[i][j][r] + bias);
      }
  }
  __syncthreads();
  {
    int r = tid >> 1, half = tid & 1;
    if (c0 + r < segc){
      u16* dst = cmb + (size_t)toks[r] * 1024 + n0 + half*64;
      const float* src = outf + r*132 + half*64;
      #pragma unroll
      for (int q = 0; q < 8; ++q){
        s16x8 o;
        if (PASS == 0){
          #pragma unroll
          for (int m = 0; m < 8; ++m) o[m] = (short)f2b(src[q*8 + m]);
        } else {
          s16x8 old = *(const s16x8*)(dst + q*8);
          #pragma unroll
          for (int m = 0; m < 8; ++m)
            o[m] = (short)f2b(b2f((u16)old[m]) + src[q*8 + m]);
        }
        *(s16x8*)(dst + q*8) = o;
      }
    }
  }
}

// ---------------- k_cls: DISJOINT: reads strided cmb [32,64M), writes cls [0,32M) ----------
// 256 rows x 128 cols per block; B dbuf 20KB; A direct-from-global bf16 strided.
__global__ __launch_bounds__(512, 4) void k_cls(
    const u16* __restrict__ cmb, const float* __restrict__ W,
    const float* __restrict__ bias, float* __restrict__ out)
{
  __shared__ __align__(16) char Bs[2][10240];   // 128 cols x 80B
  const int tid = threadIdx.x;
  const int r0  = blockIdx.x * 256;
  const int c0  = blockIdx.y * 128;

  const int bc4 = tid >> 4;          // 0..31
  const int bkp = tid & 15;          // 0..15
  u32 bpk[4];
  auto loadB = [&](int ks){
    const float* p0 = W + (size_t)(ks*32 + 2*bkp) * DOUT + c0 + bc4*4;
    f32x4 v0 = *(const f32x4*)p0;
    f32x4 v1 = *(const f32x4*)(p0 + DOUT);
    #pragma unroll
    for (int m = 0; m < 4; ++m) bpk[m] = pk2(v0[m], v1[m]);
  };
  auto writeB = [&](int buf){
    #pragma unroll
    for (int m = 0; m < 4; ++m)
      *(u32*)(Bs[buf] + (bc4*4 + m)*80 + bkp*4) = bpk[m];
  };

  const int wv = tid >> 6, lane = tid & 63;
  const int lr = lane & 15, lk = lane >> 4;
  const int rg = wv >> 1, cg = wv & 1;
  const u16* Arow = cmb + (size_t)(r0 + rg*64) * 1024;

  f32x4 acc[4][4];
  #pragma unroll
  for (int i = 0; i < 4; ++i)
    #pragma unroll
    for (int j = 0; j < 4; ++j) acc[i][j] = (f32x4){0.f,0.f,0.f,0.f};

  s16x8 af[4], afn[4];
  auto loadA = [&](s16x8* a, int ks){
    #pragma unroll
    for (int g = 0; g < 4; ++g)
      a[g] = *(const s16x8*)(Arow + (size_t)(g*16 + lr)*1024 + ks*32 + lk*8);
  };

  loadB(0); writeB(0); loadA(af, 0);
  int cur = 0;
  for (int ks = 0; ks < 16; ++ks){
    __syncthreads();
    if (ks + 1 < 16){ loadB(ks + 1); loadA(afn, ks + 1); }
    s16x8 bf[4];
    #pragma unroll
    for (int j = 0; j < 4; ++j)
      bf[j] = *(const s16x8*)(Bs[cur] + (cg*64 + j*16 + lr)*80 + lk*16);
    #pragma unroll
    for (int i = 0; i < 4; ++i)
      #pragma unroll
      for (int j = 0; j < 4; ++j)
        acc[i][j] = __builtin_amdgcn_mfma_f32_16x16x32_bf16(af[i], bf[j], acc[i][j], 0, 0, 0);
    if (ks + 1 < 16) writeB(cur ^ 1);
    #pragma unroll
    for (int g = 0; g < 4; ++g) af[g] = afn[g];
    cur ^= 1;
  }

  #pragma unroll
  for (int j = 0; j < 4; ++j){
    int col = c0 + cg*64 + j*16 + lr;
    float bv = bias[col];
    #pragma unroll
    for (int i = 0; i < 4; ++i)
      #pragma unroll
      for (int r = 0; r < 4; ++r){
        int row = r0 + rg*64 + i*16 + lk*4 + r;
        out[(size_t)row * DOUT + col] = acc[i][j][r] + bv;
      }
  }
}

// ---------------- k_vip: vec IN PLACE over [32,64M): self-contained 64-row blocks ----------
// Block's 64 output rows contain its own strided-A rows -> in-place safe after
// the drain barrier. Fast shape: B dbuf (2x40KB), A reg-prefetch, 1 barrier/step.
__global__ __launch_bounds__(512, 2) void k_vip(
    const float* __restrict__ W, const float* __restrict__ bias,
    u16* __restrict__ cmbio)
{
  __shared__ __align__(16) char Bs[2][40960];   // 512 cols x 80B each
  const int tid = threadIdx.x;
  const int r0  = blockIdx.x * 64;

  int bc4[4], bkp[4];
  #pragma unroll
  for (int u = 0; u < 4; ++u){
    int idx = tid + u*512;
    bc4[u] = idx >> 4;               // 0..127
    bkp[u] = idx & 15;               // 0..15
  }
  u32 bpk[4][4];
  auto loadB = [&](int ks){
    #pragma unroll
    for (int u = 0; u < 4; ++u){
      const float* p0 = W + (size_t)(ks*32 + 2*bkp[u]) * DOUT + bc4[u]*4;
      f32x4 v0 = *(const f32x4*)p0;
      f32x4 v1 = *(const f32x4*)(p0 + DOUT);
      #pragma unroll
      for (int m = 0; m < 4; ++m) bpk[u][m] = pk2(v0[m], v1[m]);
    }
  };
  auto writeB = [&](int buf){
    #pragma unroll
    for (int u = 0; u < 4; ++u)
      #pragma unroll
      for (int m = 0; m < 4; ++m)
        *(u32*)(Bs[buf] + (bc4[u]*4 + m)*80 + bkp[u]*4) = bpk[u][m];
  };

  const int wv = tid >> 6, lane = tid & 63;
  const int lr = lane & 15, lk = lane >> 4;
  const int wc = wv * 64;
  const u16* Arow = cmbio + (size_t)r0 * 1024;

  f32x4 acc[4][4];
  #pragma unroll
  for (int i = 0; i < 4; ++i)
    #pragma unroll
    for (int j = 0; j < 4; ++j) acc[i][j] = (f32x4){0.f,0.f,0.f,0.f};

  s16x8 af[4], afn[4];
  auto loadA = [&](s16x8* a, int ks){
    #pragma unroll
    for (int g = 0; g < 4; ++g)
      a[g] = *(const s16x8*)(Arow + (size_t)(g*16 + lr)*1024 + ks*32 + lk*8);
  };

  loadB(0); writeB(0); loadA(af, 0);
  int cur = 0;
  for (int ks = 0; ks < 16; ++ks){
    __syncthreads();                 // Bs[cur] ready; prior reads drained
    if (ks + 1 < 16){ loadB(ks + 1); loadA(afn, ks + 1); }
    s16x8 bf[4];
    #pragma unroll
    for (int g = 0; g < 4; ++g)
      bf[g] = *(const s16x8*)(Bs[cur] + (wc + g*16 + lr)*80 + lk*16);
    #pragma unroll
    for (int i = 0; i < 4; ++i)
      #pragma unroll
      for (int j = 0; j < 4; ++j)
        acc[i][j] = __builtin_amdgcn_mfma_f32_16x16x32_bf16(af[i], bf[j], acc[i][j], 0, 0, 0);
    if (ks + 1 < 16) writeB(cur ^ 1);
    #pragma unroll
    for (int g = 0; g < 4; ++g) af[g] = afn[g];
    cur ^= 1;
  }
  __syncthreads();   // drain all waves' A reads (vmcnt 0) before in-place overwrite

  float* out = (float*)cmbio;        // f32 view, row stride DOUT
  #pragma unroll
  for (int j = 0; j < 4; ++j){
    int col = wc + j*16 + lr;
    float bv = bias[col];
    #pragma unroll
    for (int i = 0; i < 4; ++i)
      #pragma unroll
      for (int r = 0; r < 4; ++r){
        int row = r0 + i*16 + lk*4 + r;
        out[(size_t)row * DOUT + col] = acc[i][j][r] + bv;
      }
  }
}

extern "C" void kernel_launch(void* const* d_in, const int* in_sizes, int n_in,
                              void* d_out, int out_size, void* d_ws, size_t ws_size,
                              hipStream_t stream)
{
  const float* x    = (const float*)d_in[0];
  const float* gw   = (const float*)d_in[1];
  const float* gb   = (const float*)d_in[2];
  const float* w1   = (const float*)d_in[3];
  const float* b1   = (const float*)d_in[4];
  const float* w2   = (const float*)d_in[5];
  const float* b2   = (const float*)d_in[6];
  const float* clsw = (const float*)d_in[7];
  const float* clsb = (const float*)d_in[8];
  const float* vecw = (const float*)d_in[9];
  const float* vecb = (const float*)d_in[10];

  char* base = (char*)d_out;
  float* cls_out  = (float*)base;                               // [0,32Mi)
  u16*   cmb      = (u16*)(base + ((size_t)32<<20));            // strided in vec half
  // scratch inside cls half; all dead before k_cls writes [0,32Mi):
  u16*   h        = (u16*)base;                                 // [0,16Mi) bf16[32768][256]
  char*  mb       = base + ((size_t)16<<20) + (128<<10);        // 128K overrun pad after h
  int*   tok_slot = (int*)  mb;
  float* w_slot   = (float*)(mb + 131072);
  int*   tke      = (int*)  (mb + 262144);
  float* tkw      = (float*)(mb + 393216);
  int*   counts   = (int*)  (mb + 524288);
  int*   offsets  = (int*)  (mb + 524544);
  int*   cursors  = (int*)  (mb + 524800);
  u16*   w1tb     = (u16*)(base + ((size_t)18<<20));
  u16*   w2tb     = (u16*)(base + ((size_t)21<<20));

  k_zero<<<dim3(1), dim3(64), 0, stream>>>(counts);
  k_gate<<<dim3(NTOK/4), dim3(256), 0, stream>>>(x, gw, gb, tke, tkw, counts);
  k_scan<<<dim3(1), dim3(64), 0, stream>>>(counts, offsets, cursors);
  k_scatter<<<dim3(NTOK/256), dim3(256), 0, stream>>>(tke, tkw, offsets, cursors,
                                                      tok_slot, w_slot);
  k_wt<<<dim3(HDIM/32, DIN/32, NEXP), dim3(256), 0, stream>>>(w1, w1tb, DIN, HDIM);
  k_wt<<<dim3(DOUT/32, HDIM/32, NEXP), dim3(256), 0, stream>>>(w2, w2tb, HDIM, DOUT);
  k_h<<<dim3(256, 2, NEXP), dim3(256), 0, stream>>>(x, w1tb, b1, offsets, tok_slot, h);
  k_y<0><<<dim3(128, 4, NEXP), dim3(256), 0, stream>>>(h, w2tb, b2, offsets, tok_slot, w_slot, cmb);
  k_y<1><<<dim3(128, 4, NEXP), dim3(256), 0, stream>>>(h, w2tb, b2, offsets, tok_slot, w_slot, cmb);
  // cls: reads cmb [32,64Mi), writes [0,32Mi) — disjoint, fast shape.
  k_cls<<<dim3(NTOK/256, DOUT/128), dim3(512), 0, stream>>>(cmb, clsw, clsb, cls_out);
  // vec last: in place over [32,64Mi), self-contained rows.
  k_vip<<<dim3(NTOK/64), dim3(512), 0, stream>>>(vecw, vecb, cmb);
}